// Round 3
// baseline (398.971 us; speedup 1.0000x reference)
//
#include <hip/hip_runtime.h>
#include <hip/hip_bf16.h>
#include <math.h>

#define BB 2
#define D 48
#define HH 64
#define WW 64
#define LL 4096      // HH*WW
#define NHEADS 4
#define HD 12
#define NBLK 4
#define CUP 768
#define H2 256
#define W2 256

#define NSPLIT 4
#define OPART_STRIDE 393216   // B*L*48 floats per split

typedef __attribute__((ext_vector_type(8))) short short8v;
typedef __attribute__((ext_vector_type(4))) float f32x4;
typedef unsigned long long u64;

__device__ __forceinline__ short f2bf(float f) {
    __hip_bfloat16 h = __float2bfloat16(f);
    union { __hip_bfloat16 b; short s; } u; u.b = h; return u.s;
}
__device__ __forceinline__ float bf2f(short s) {
    union { float f; unsigned u; } x;
    x.u = ((unsigned)(unsigned short)s) << 16;
    return x.f;
}
// raw 2^x (hardware approx, ~1 ulp; inputs are tiny softmax scores -> safe)
__device__ __forceinline__ float exp2_raw(float x) {
    float r; asm("v_exp_f32 %0, %1" : "=v"(r) : "v"(x)); return r;
}

// ---------------- generic 3x3 SAME conv, f32 (used for conv_first only) ----------------
__global__ void conv3x3_kernel(const float* __restrict__ in, const float* __restrict__ w,
                               const float* __restrict__ bias, float* __restrict__ out,
                               int Cin, int Cout) {
    int idx = blockIdx.x * blockDim.x + threadIdx.x;
    int total = BB * Cout * HH * WW;
    if (idx >= total) return;
    int x = idx % WW;
    int y = (idx / WW) % HH;
    int co = (idx / (WW * HH)) % Cout;
    int b = idx / (WW * HH * Cout);
    float s = bias[co];
    for (int ci = 0; ci < Cin; ci++) {
        const float* ip = in + ((size_t)(b * Cin + ci) * HH) * WW;
        const float* wp = w + (size_t)(co * Cin + ci) * 9;
        #pragma unroll
        for (int ky = 0; ky < 3; ky++) {
            int iy = y + ky - 1;
            if (iy < 0 || iy >= HH) continue;
            #pragma unroll
            for (int kx = 0; kx < 3; kx++) {
                int ix = x + kx - 1;
                if (ix < 0 || ix >= WW) continue;
                s += ip[iy * WW + ix] * wp[ky * 3 + kx];
            }
        }
    }
    out[idx] = s;
}

// ---- pack h (NCHW f32) -> bf16 channel-last with 1-px zero halo: [b][66][66][48] + 64 zero ----
__global__ __launch_bounds__(256) void pack_h_kernel(const float* __restrict__ h,
                                                     short* __restrict__ hbfp) {
    int idx = blockIdx.x * 256 + threadIdx.x;
    const int TOT = 2 * 66 * 66 * 48;    // 418176
    if (idx >= TOT + 64) return;
    if (idx >= TOT) { hbfp[idx] = 0; return; }
    int ci = idx % 48;
    int p = idx / 48;
    int xx = p % 66;
    int q = p / 66;
    int yy = q % 66;
    int b = q / 66;
    short v = 0;
    if (yy >= 1 && yy <= 64 && xx >= 1 && xx <= 64)
        v = f2bf(h[((size_t)(b * 48 + ci) << 12) + (yy - 1) * 64 + (xx - 1)]);
    hbfp[idx] = v;
}

// ---- pack conv_up weights into B-fragment order: Wp[n16][s][col][g][j], K=tap*48+ci pad 448 ----
__global__ __launch_bounds__(256) void pack_w_kernel(const float* __restrict__ w,
                                                     short* __restrict__ Wp) {
    int idx = blockIdx.x * 256 + threadIdx.x;
    if (idx >= 48 * 14 * 512) return;    // 344064
    int j = idx & 7;
    int g = (idx >> 3) & 3;
    int col = (idx >> 5) & 15;
    int s = (idx >> 9) % 14;
    int n16 = idx / (14 * 512);
    int k = 32 * s + 8 * g + j;
    short v = 0;
    if (k < 432) {
        int tap = k / 48, ci = k - tap * 48;
        int co = n16 * 16 + col;
        v = f2bf(w[((size_t)co * 48 + ci) * 9 + tap]);
    }
    Wp[idx] = v;
}

// ---- conv_up as bf16 MFMA GEMM: M=8192 px, N=768 co, K=448; pixel-shuffle bf16 write ----
__global__ __launch_bounds__(256) void conv_up_mfma_kernel(const short* __restrict__ hbfp,
                                                           const short* __restrict__ Wp,
                                                           const float* __restrict__ bias,
                                                           short* __restrict__ U) {
    int tid = threadIdx.x;
    int wave = tid >> 6, lane = tid & 63;
    int t = blockIdx.x * 4 + wave;          // 24576 tiles
    int mt = t / 48;
    int n16 = t - mt * 48;
    int b = mt >> 8;
    int rem = mt & 255;
    int y = rem >> 2;
    int xt = rem & 3;
    int col = lane & 15;
    int g = lane >> 4;
    int x = xt * 16 + col;                  // A-row pixel x

    const short* Bp = Wp + (size_t)n16 * (14 * 512) + col * 32 + g * 8;
    const short* zb = hbfp + 2 * 66 * 66 * 48;   // 64 zero shorts

    f32x4 acc = {0.f, 0.f, 0.f, 0.f};
    #pragma unroll
    for (int s = 0; s < 14; s++) {
        int gg = 4 * s + g;
        int tap = (gg * 171) >> 10;         // gg/6 for gg<60
        int cig = gg - tap * 6;
        int dy = (tap * 11) >> 5;           // tap/3 for tap<9(+)
        int dx = tap - dy * 3;
        const short* ap = hbfp + ((size_t)((b * 66 + y + dy) * 66 + (x + dx)) * 48 + cig * 8);
        ap = (gg < 54) ? ap : zb;
        short8v av = *(const short8v*)ap;
        short8v bv = *(const short8v*)(Bp + s * 512);
        acc = __builtin_amdgcn_mfma_f32_16x16x32_bf16(av, bv, acc, 0, 0, 0);
    }

    int co = n16 * 16 + col;
    float bval = bias[co];
    int ic = co >> 4, dyq = (co >> 2) & 3, dxq = co & 3;
    short* Ur = U + ((size_t)(b * 48 + ic) * 256 + 4 * y + dyq) * 256 + dxq;
    #pragma unroll
    for (int j = 0; j < 4; j++) {
        int r = 4 * g + j;                  // C row = pixel-x offset (m89 mapping)
        Ur[4 * (xt * 16 + r)] = f2bf(acc[j] + bval);
    }
}

// ---- zero bf16 pad regions; plant bf16 1.0 in Vr's padded row dd==12 (sum-row trick) ----
__global__ void zero16_kernel(u64* __restrict__ p, int n) {
    int i = blockIdx.x * 256 + threadIdx.x;
    if (i >= n) return;
    u64 fill = 0ull;
    // short offset of this 8-short chunk, relative to Vr start (Q:1M + K:1M shorts before it)
    int rel = 8 * i - 2097152;
    if (rel >= 0 && rel < 524288 && (((rel >> 5) & 15) == 12))
        fill = 0x3F803F803F803F80ull;     // bf16 1.0 x4
    p[2 * i] = fill;
    p[2 * i + 1] = fill;
}

// ---- fused: LN1 (NCHW) -> ln1 rows + qkv matmul -> bf16 Q/K/Vr (16-tok tiles) ----
__global__ __launch_bounds__(256) void fused_ln1_qkv_kernel(
    const float* __restrict__ hsrc, const float* __restrict__ g1, const float* __restrict__ b1,
    const float* __restrict__ w, const float* __restrict__ bias,
    float* __restrict__ ln1, short* __restrict__ Qbf, short* __restrict__ Kbf,
    short* __restrict__ Vr) {
    __shared__ float hs[48 * 17];
    __shared__ float lnr[16 * 49];
    __shared__ float wl[48 * 144];
    int blk = blockIdx.x;
    int b = blk >> 8;
    int pos0 = (blk & 255) * 16;
    int tid = threadIdx.x;

    for (int i = tid; i < 48 * 144; i += 256) wl[i] = w[i];
    for (int i = tid; i < 48 * 16; i += 256) {
        int ch = i >> 4, p = i & 15;
        hs[ch * 17 + p] = hsrc[((size_t)b * 48 + ch) * 4096 + pos0 + p];
    }
    __syncthreads();

    int tok = tid >> 4, oct = tid & 15;
    int pos = pos0 + tok;
    float v[3];
    float s = 0.f, s2 = 0.f;
    #pragma unroll
    for (int j = 0; j < 3; j++) {
        float x = hs[(oct * 3 + j) * 17 + tok];
        v[j] = x; s += x; s2 += x * x;
    }
    #pragma unroll
    for (int msk = 1; msk < 16; msk <<= 1) {
        s += __shfl_xor(s, msk, 64);
        s2 += __shfl_xor(s2, msk, 64);
    }
    float mu = s * (1.f / 48.f);
    float var = s2 * (1.f / 48.f) - mu * mu;
    float rs = rsqrtf(var + 1e-5f);
    float* go = ln1 + ((size_t)b * 4096 + pos) * 48 + oct * 3;
    #pragma unroll
    for (int j = 0; j < 3; j++) {
        int c = oct * 3 + j;
        float y = (v[j] - mu) * rs * g1[c] + b1[c];
        lnr[tok * 49 + c] = y;
        go[j] = y;
    }
    __syncthreads();

    int c0 = oct * 9;
    float acc[9];
    #pragma unroll
    for (int j = 0; j < 9; j++) acc[j] = bias[c0 + j];
    #pragma unroll 4
    for (int k = 0; k < 48; k++) {
        float a = lnr[tok * 49 + k];
        const float* wr = wl + k * 144 + c0;
        #pragma unroll
        for (int j = 0; j < 9; j++) acc[j] += a * wr[j];
    }

    // 1/sqrt(12) * log2(e): softmax exp becomes a single raw v_exp_f32 (2^x)
    const float scale = 0.41647023f;
    int sstep = pos >> 5, r = pos & 31;
    int g2 = (r < 16) ? (r >> 2) : ((r - 16) >> 2);
    int j2 = (r < 16) ? (r & 3) : 4 + ((r - 16) & 3);
    #pragma unroll
    for (int j = 0; j < 9; j++) {
        int c = c0 + j;
        int which = (c >= 96) ? 2 : (c >= 48 ? 1 : 0);
        int rem = c - which * 48;
        int hh = rem / 12;
        int dd = rem - hh * 12;
        int bh = b * 4 + hh;
        if (which == 0)
            Qbf[((size_t)bh * 4096 + pos) * 32 + dd] = f2bf(acc[j] * scale);
        else if (which == 1)
            Kbf[((size_t)bh * 4096 + pos) * 32 + dd] = f2bf(acc[j]);
        else
            Vr[((size_t)bh * 128 + sstep) * 512 + dd * 32 + g2 * 8 + j2] = f2bf(acc[j]);
    }
}

// ---- fused: split-combine + proj + resid + LN2 + fc1 + GELU + fc2 + resid + h-accum ----
__global__ __launch_bounds__(256) void fused_mlp_kernel(
    const float* __restrict__ opart, const float* __restrict__ ssump,
    const float* __restrict__ pwg, const float* __restrict__ pb,
    const float* __restrict__ ln1, const float* __restrict__ g2v, const float* __restrict__ b2v,
    const float* __restrict__ f1w, const float* __restrict__ f1b,
    const float* __restrict__ f2w, const float* __restrict__ f2b,
    float* __restrict__ hbuf) {
    __shared__ float sm[14640];
    float* wp  = sm;            // 2304  (48x48 proj)
    float* w1  = sm + 2304;     // 4608  (48x96 fc1)
    float* w2  = sm + 6912;     // 4608  (96x48 fc2)
    float* arf = sm + 11520;    // 784   (16x49) attn rows, reused as fc2-out
    float* lnr = sm + 12304;    // 784   (16x49) ln2 rows
    float* m1v = sm + 13088;    // 1552  (16x97) gelu(fc1)

    int blk = blockIdx.x;
    int b = blk >> 8;
    int pos0 = (blk & 255) * 16;
    int tid = threadIdx.x;

    for (int i = tid; i < 2304; i += 256) wp[i] = pwg[i];
    for (int i = tid; i < 4608; i += 256) w1[i] = f1w[i];
    for (int i = tid; i < 4608; i += 256) w2[i] = f2w[i];
    // combine split partials -> normalized attention rows (per-thread, no extra sync deps)
    for (int i = tid; i < 768; i += 256) {
        int t = i / 48, c = i - (i / 48) * 48;
        int hh = c / 12;
        size_t base = ((size_t)b * 4096 + pos0) * 48 + i;
        float stot = 0.f, s = 0.f;
        #pragma unroll
        for (int sp = 0; sp < NSPLIT; sp++) {
            stot += ssump[((size_t)sp * 8 + b * 4 + hh) * 4096 + pos0 + t];
            s += opart[base + (size_t)sp * OPART_STRIDE];
        }
        arf[t * 49 + c] = s / stot;
    }
    __syncthreads();

    int tok = tid >> 4, oct = tid & 15;
    size_t gtok = (size_t)b * 4096 + pos0 + tok;
    int c0 = oct * 3;
    float acc[3];
    #pragma unroll
    for (int j = 0; j < 3; j++) acc[j] = pb[c0 + j];
    #pragma unroll 4
    for (int k = 0; k < 48; k++) {
        float a = arf[tok * 49 + k];
        const float* wr = wp + k * 48 + c0;
        #pragma unroll
        for (int j = 0; j < 3; j++) acc[j] += a * wr[j];
    }
    const float* rp = ln1 + gtok * 48 + c0;
    float x[3]; float s = 0.f, s2 = 0.f;
    #pragma unroll
    for (int j = 0; j < 3; j++) {
        float t = acc[j] + rp[j];
        x[j] = t; s += t; s2 += t * t;
    }
    #pragma unroll
    for (int msk = 1; msk < 16; msk <<= 1) {
        s += __shfl_xor(s, msk, 64);
        s2 += __shfl_xor(s2, msk, 64);
    }
    float mu = s * (1.f / 48.f), var = s2 * (1.f / 48.f) - mu * mu;
    float rs = rsqrtf(var + 1e-5f);
    #pragma unroll
    for (int j = 0; j < 3; j++) {
        int c = c0 + j;
        lnr[tok * 49 + c] = (x[j] - mu) * rs * g2v[c] + b2v[c];
    }
    __syncthreads();

    // fc1 + GELU -> m1v (LDS only)
    int d0 = oct * 6;
    float a2[6];
    #pragma unroll
    for (int j = 0; j < 6; j++) a2[j] = f1b[d0 + j];
    #pragma unroll 4
    for (int k = 0; k < 48; k++) {
        float a = lnr[tok * 49 + k];
        const float* wr = w1 + k * 96 + d0;
        #pragma unroll
        for (int j = 0; j < 6; j++) a2[j] += a * wr[j];
    }
    #pragma unroll
    for (int j = 0; j < 6; j++) {
        float g = a2[j];
        m1v[tok * 97 + d0 + j] = 0.5f * g * (1.f + erff(g * 0.70710678118654752f));
    }
    __syncthreads();

    // fc2 + ln2-residual -> arf (reused)
    float f2acc[3];
    #pragma unroll
    for (int j = 0; j < 3; j++) f2acc[j] = f2b[c0 + j];
    #pragma unroll 4
    for (int k = 0; k < 96; k++) {
        float a = m1v[tok * 97 + k];
        const float* wr = w2 + k * 48 + c0;
        #pragma unroll
        for (int j = 0; j < 3; j++) f2acc[j] += a * wr[j];
    }
    __syncthreads();
    #pragma unroll
    for (int j = 0; j < 3; j++)
        arf[tok * 49 + c0 + j] = f2acc[j] + lnr[tok * 49 + c0 + j];
    __syncthreads();

    // cooperative coalesced transposed accumulate into h (NCHW)
    for (int i = tid; i < 768; i += 256) {
        int c = i >> 4, t = i & 15;
        hbuf[(((size_t)(b * 48 + c)) << 12) + pos0 + t] += arf[t * 49 + c];
    }
}

// ---- MFMA flash attention: 16 q/wave, swapped QK^T, 128-key register-prefetch pipeline,
//      split-K x4 (1024 keys/block). No-max softmax (scores |s|<<1): partials (o, sum p)
//      are plain sums -> additive combine in fused_mlp. Row sum via V ones-row (dd==12).
#define LOADCH(P, c) { \
    _Pragma("unroll") \
    for (int s_ = 0; s_ < 4; s_++) { \
        const short* kp_ = Kb + ((size_t)((c) * 128 + s_ * 32 + col)) * 32 + g * 8; \
        P##k0[s_] = *(const short8v*)(kp_); \
        P##k1[s_] = *(const short8v*)(kp_ + 512); \
        P##v[s_]  = *(const short8v*)(Vrb + ((c) * 4 + s_) * 512 + vbase); \
    } }

#define STEP(kc0, kc1, vv) { \
    f32x4 z_ = {0.f, 0.f, 0.f, 0.f}; \
    f32x4 s1 = __builtin_amdgcn_mfma_f32_16x16x32_bf16(kc0, qb, z_, 0, 0, 0); \
    f32x4 s2 = __builtin_amdgcn_mfma_f32_16x16x32_bf16(kc1, qb, z_, 0, 0, 0); \
    float p0 = exp2_raw(s1[0]), p1 = exp2_raw(s1[1]); \
    float p2 = exp2_raw(s1[2]), p3 = exp2_raw(s1[3]); \
    float p4 = exp2_raw(s2[0]), p5 = exp2_raw(s2[1]); \
    float p6 = exp2_raw(s2[2]), p7 = exp2_raw(s2[3]); \
    union { short8v sv; unsigned u[4]; } pbu; \
    asm("v_cvt_pk_bf16_f32 %0, %1, %2" : "=v"(pbu.u[0]) : "v"(p0), "v"(p1)); \
    asm("v_cvt_pk_bf16_f32 %0, %1, %2" : "=v"(pbu.u[1]) : "v"(p2), "v"(p3)); \
    asm("v_cvt_pk_bf16_f32 %0, %1, %2" : "=v"(pbu.u[2]) : "v"(p4), "v"(p5)); \
    asm("v_cvt_pk_bf16_f32 %0, %1, %2" : "=v"(pbu.u[3]) : "v"(p6), "v"(p7)); \
    o = __builtin_amdgcn_mfma_f32_16x16x32_bf16(vv, pbu.sv, o, 0, 0, 0); }

#define COMPUTECH(P) { \
    STEP(P##k0[0], P##k1[0], P##v[0]); \
    STEP(P##k0[1], P##k1[1], P##v[1]); \
    STEP(P##k0[2], P##k1[2], P##v[2]); \
    STEP(P##k0[3], P##k1[3], P##v[3]); }

__global__ __launch_bounds__(256) void attn_mfma_kernel(const short* __restrict__ Qbf,
                                                        const short* __restrict__ Kbf,
                                                        const short* __restrict__ Vr,
                                                        float* __restrict__ opart,
                                                        float* __restrict__ ssump) {
    int bid = blockIdx.x;                 // split(4) | qblk(64) | bh(8) = 2048 blocks
    int bh = bid & 7;
    int qblk = (bid >> 3) & 63;
    int split = bid >> 9;
    int h = bh & 3, b = bh >> 2;
    int tid = threadIdx.x;
    int wave = tid >> 6;
    int lane = tid & 63;
    int q0 = qblk * 64 + wave * 16;
    int col = lane & 15;
    int g = lane >> 4;

    const short* Kb  = Kbf + (size_t)bh * LL * 32 + (size_t)split * 1024 * 32;
    const short* Vrb = Vr + (size_t)bh * 65536 + (size_t)split * 32 * 512;
    int vbase = col * 32 + g * 8;

    short8v qb = *(const short8v*)(Qbf + ((size_t)bh * LL + q0 + col) * 32 + g * 8);

    f32x4 o = {0.f, 0.f, 0.f, 0.f};

    short8v a_k0[4], a_k1[4], a_v[4];
    short8v b_k0[4], b_k1[4], b_v[4];

    LOADCH(a_, 0);
    for (int c = 0; c < 8; c += 2) {
        LOADCH(b_, c + 1);
        COMPUTECH(a_);
        if (c + 2 < 8) LOADCH(a_, c + 2);
        COMPUTECH(b_);
    }

    // row 12 of o (lane group g==3, j==0) holds this split's sum(p) via V's ones-row
    float ssum = __shfl(o[0], 48 + col, 64);

    float* op = opart + (size_t)split * OPART_STRIDE
              + ((size_t)b * 4096 + q0 + col) * 48 + h * HD;
    #pragma unroll
    for (int j = 0; j < 4; j++) {
        int d = 4 * g + j;
        if (d < HD)
            op[d] = o[j];
    }
    if (lane < 16)
        ssump[((size_t)split * 8 + bh) * 4096 + q0 + col] = ssum;
}

// ---- last conv: 3x3 over bf16 U, 4-row x 32-col tiles, stage-split dbuf, grid 1024 ----
#define LW2 36
__global__ __launch_bounds__(128) void lastconv_kernel(const short* __restrict__ U,
                                                       const float* __restrict__ w,
                                                       const float* __restrict__ bias,
                                                       float* __restrict__ out) {
    int blk = blockIdx.x;          // xt(8: 32-col), yt(64: 4-row), b(2) -> 1024 blocks
    int xt = blk & 7;
    int yt = (blk >> 3) & 63;
    int b = blk >> 9;
    int tid = threadIdx.x;
    int xx = tid & 31;
    int yy = tid >> 5;             // 0..3
    int y0 = yt * 4;
    int x0t = xt * 32;
    int y = y0 + yy;
    int x = x0t + xx;

    __shared__ float wl[3 * 48 * 9];
    __shared__ float tile[2][6 * LW2];
    for (int i = tid; i < 3 * 48 * 9; i += 128) wl[i] = w[i];

    const short* Ub = U + (size_t)b * 48 * 65536;

    // staging: 6 rows x 34 cols = 204 slots, 128 thr -> 2 chunks
    int soff[2]; int doff[2]; bool sval[2]; bool swr[2];
    #pragma unroll
    for (int kk = 0; kk < 2; kk++) {
        int i = tid + kk * 128;
        int r = i / 34, c = i - r * 34;
        int gy = y0 - 1 + r, gx = x0t - 1 + c;
        bool inb_ok = (i < 204);
        bool ok = inb_ok && (gy >= 0 && gy < 256 && gx >= 0 && gx < 256);
        swr[kk] = inb_ok;
        sval[kk] = ok;
        doff[kk] = inb_ok ? r * LW2 + c : 0;
        soff[kk] = ok ? gy * 256 + gx : 0;
    }

    {
        float* tb = tile[0];
        #pragma unroll
        for (int kk = 0; kk < 2; kk++)
            if (swr[kk]) tb[doff[kk]] = sval[kk] ? bf2f(Ub[soff[kk]]) : 0.f;
    }

    float acc[3];
    #pragma unroll
    for (int oc = 0; oc < 3; oc++) acc[oc] = bias[oc];
    __syncthreads();

    for (int ci = 0; ci < 48; ci++) {
        float rr[2];
        if (ci + 1 < 48) {
            const short* ip = Ub + (size_t)(ci + 1) * 65536;
            #pragma unroll
            for (int kk = 0; kk < 2; kk++)
                rr[kk] = sval[kk] ? bf2f(ip[soff[kk]]) : 0.f;
        }
        const float* tp = tile[ci & 1];
        float row[3][3];
        #pragma unroll
        for (int ky = 0; ky < 3; ky++) {
            const float* rp = tp + (yy + ky) * LW2 + xx;
            #pragma unroll
            for (int dx = 0; dx < 3; dx++) row[ky][dx] = rp[dx];
        }
        #pragma unroll
        for (int oc = 0; oc < 3; oc++) {
            const float* wp = wl + (oc * 48 + ci) * 9;
            acc[oc] += wp[0] * row[0][0] + wp[1] * row[0][1] + wp[2] * row[0][2]
                     + wp[3] * row[1][0] + wp[4] * row[1][1] + wp[5] * row[1][2]
                     + wp[6] * row[2][0] + wp[7] * row[2][1] + wp[8] * row[2][2];
        }
        if (ci + 1 < 48) {
            float* tb = tile[(ci + 1) & 1];
            #pragma unroll
            for (int kk = 0; kk < 2; kk++)
                if (swr[kk]) tb[doff[kk]] = rr[kk];
        }
        __syncthreads();
    }
    #pragma unroll
    for (int oc = 0; oc < 3; oc++)
        out[(((size_t)(b * 3 + oc) * 256) + y) * 256 + x] = acc[oc];
}

static inline int gs(int n) { return (n + 255) / 256; }

extern "C" void kernel_launch(void* const* d_in, const int* in_sizes, int n_in,
                              void* d_out, int out_size, void* d_ws, size_t ws_size,
                              hipStream_t stream) {
    const float* x    = (const float*)d_in[0];
    const float* cf_w = (const float*)d_in[1];
    const float* cf_b = (const float*)d_in[2];
    const float* n1g  = (const float*)d_in[3];
    const float* n1b  = (const float*)d_in[4];
    const float* qkvw = (const float*)d_in[5];
    const float* qkvb = (const float*)d_in[6];
    const float* pw   = (const float*)d_in[7];
    const float* pb   = (const float*)d_in[8];
    const float* n2g  = (const float*)d_in[9];
    const float* n2b  = (const float*)d_in[10];
    const float* f1w  = (const float*)d_in[11];
    const float* f1b  = (const float*)d_in[12];
    const float* f2w  = (const float*)d_in[13];
    const float* f2b  = (const float*)d_in[14];
    const float* upw  = (const float*)d_in[15];
    const float* upb  = (const float*)d_in[16];
    const float* lw   = (const float*)d_in[17];
    const float* lb   = (const float*)d_in[18];

    float* ws = (float*)d_ws;
    const int S_h = BB * D * LL;            // 393216
    float* A_h   = ws;
    float* pool  = ws + S_h;
    float* A_ln1 = pool;

    // U now bf16: [b][48][256][256] shorts = 3145728 floats-worth at pool[0]
    short* U_bf = (short*)pool;
    // attention split partials: o_part [4][B*L*48] in the old A_att slot + free gap
    float* o_part = pool + 1572864;                    // 4*393216 = 1572864 floats, ends 3145728
    // packs live between o_part end and Qbf start
    short* hbfp = (short*)(pool + 3145728);            // 418240 shorts (incl. 64 zero pad)
    short* Wp   = (short*)(pool + 3145728 + 209120);   // 344064 shorts
    short* Qbf  = (short*)(pool + 3538944);
    short* Kbf  = Qbf + BB * NHEADS * LL * 32;
    short* Vr   = Kbf + BB * NHEADS * LL * 32;
    // ssum partials after Vr end (pool+5898240), 4*8*4096 = 131072 floats < old footprint
    float* ssum_part = pool + 5898240;

    // conv_first (3 -> 48)
    conv3x3_kernel<<<gs(S_h), 256, 0, stream>>>(x, cf_w, cf_b, A_h, 3, D);

    // zero Q/K/Vr (pads must be 0; Vr ones-row planted; real entries overwritten every block)
    zero16_kernel<<<1536, 256, 0, stream>>>((u64*)Qbf, 393216);
    // pack conv_up weights (input-only dependency)
    pack_w_kernel<<<1344, 256, 0, stream>>>(upw, Wp);

    for (int i = 0; i < NBLK; i++) {
        fused_ln1_qkv_kernel<<<512, 256, 0, stream>>>(
            A_h, n1g + i * D, n1b + i * D,
            qkvw + (size_t)i * D * 3 * D, qkvb + i * 3 * D,
            A_ln1, Qbf, Kbf, Vr);
        attn_mfma_kernel<<<8 * 64 * NSPLIT, 256, 0, stream>>>(Qbf, Kbf, Vr, o_part, ssum_part);
        fused_mlp_kernel<<<512, 256, 0, stream>>>(
            o_part, ssum_part, pw + (size_t)i * D * D, pb + i * D,
            A_ln1, n2g + i * D, n2b + i * D,
            f1w + (size_t)i * D * 2 * D, f1b + i * 2 * D,
            f2w + (size_t)i * 2 * D * D, f2b + i * D,
            A_h);
    }

    // pack h -> bf16 halo'd channel-last, then MFMA GEMM conv_up (+pixel shuffle, bf16 U)
    pack_h_kernel<<<1634, 256, 0, stream>>>(A_h, hbfp);
    conv_up_mfma_kernel<<<6144, 256, 0, stream>>>(hbfp, Wp, upb, U_bf);

    // last conv: plain 3x3 over bf16 U -> f32 out
    lastconv_kernel<<<1024, 128, 0, stream>>>(U_bf, lw, lb, (float*)d_out);
}

// Round 4
// 322.613 us; speedup vs baseline: 1.2367x; 1.2367x over previous
//
#include <hip/hip_runtime.h>
#include <hip/hip_bf16.h>
#include <math.h>

#define BB 2
#define D 48
#define HH 64
#define WW 64
#define LL 4096      // HH*WW
#define NHEADS 4
#define HD 12
#define NBLK 4
#define CUP 768
#define H2 256
#define W2 256

#define NSPLIT 4
#define OPART_STRIDE 393216   // B*L*48 floats per split

typedef __attribute__((ext_vector_type(8))) short short8v;
typedef __attribute__((ext_vector_type(4))) float f32x4;
typedef unsigned long long u64;

__device__ __forceinline__ short f2bf(float f) {
    __hip_bfloat16 h = __float2bfloat16(f);
    union { __hip_bfloat16 b; short s; } u; u.b = h; return u.s;
}
__device__ __forceinline__ float bf2f(short s) {
    union { float f; unsigned u; } x;
    x.u = ((unsigned)(unsigned short)s) << 16;
    return x.f;
}
// raw 2^x (hardware approx, ~1 ulp; inputs are tiny softmax scores -> safe)
__device__ __forceinline__ float exp2_raw(float x) {
    float r; asm("v_exp_f32 %0, %1" : "=v"(r) : "v"(x)); return r;
}

// ---------------- generic 3x3 SAME conv, f32 (used for conv_first only) ----------------
__global__ void conv3x3_kernel(const float* __restrict__ in, const float* __restrict__ w,
                               const float* __restrict__ bias, float* __restrict__ out,
                               int Cin, int Cout) {
    int idx = blockIdx.x * blockDim.x + threadIdx.x;
    int total = BB * Cout * HH * WW;
    if (idx >= total) return;
    int x = idx % WW;
    int y = (idx / WW) % HH;
    int co = (idx / (WW * HH)) % Cout;
    int b = idx / (WW * HH * Cout);
    float s = bias[co];
    for (int ci = 0; ci < Cin; ci++) {
        const float* ip = in + ((size_t)(b * Cin + ci) * HH) * WW;
        const float* wp = w + (size_t)(co * Cin + ci) * 9;
        #pragma unroll
        for (int ky = 0; ky < 3; ky++) {
            int iy = y + ky - 1;
            if (iy < 0 || iy >= HH) continue;
            #pragma unroll
            for (int kx = 0; kx < 3; kx++) {
                int ix = x + kx - 1;
                if (ix < 0 || ix >= WW) continue;
                s += ip[iy * WW + ix] * wp[ky * 3 + kx];
            }
        }
    }
    out[idx] = s;
}

// ---- pack h (NCHW f32) -> bf16 channel-last with 1-px zero halo: [b][66][66][48] + 64 zero ----
__global__ __launch_bounds__(256) void pack_h_kernel(const float* __restrict__ h,
                                                     short* __restrict__ hbfp) {
    int idx = blockIdx.x * 256 + threadIdx.x;
    const int TOT = 2 * 66 * 66 * 48;    // 418176
    if (idx >= TOT + 64) return;
    if (idx >= TOT) { hbfp[idx] = 0; return; }
    int ci = idx % 48;
    int p = idx / 48;
    int xx = p % 66;
    int q = p / 66;
    int yy = q % 66;
    int b = q / 66;
    short v = 0;
    if (yy >= 1 && yy <= 64 && xx >= 1 && xx <= 64)
        v = f2bf(h[((size_t)(b * 48 + ci) << 12) + (yy - 1) * 64 + (xx - 1)]);
    hbfp[idx] = v;
}

// ---- pack conv_up weights into B-fragment order: Wp[n16][s][col][g][j], K=tap*48+ci pad 448 ----
__global__ __launch_bounds__(256) void pack_w_kernel(const float* __restrict__ w,
                                                     short* __restrict__ Wp) {
    int idx = blockIdx.x * 256 + threadIdx.x;
    if (idx >= 48 * 14 * 512) return;    // 344064
    int j = idx & 7;
    int g = (idx >> 3) & 3;
    int col = (idx >> 5) & 15;
    int s = (idx >> 9) % 14;
    int n16 = idx / (14 * 512);
    int k = 32 * s + 8 * g + j;
    short v = 0;
    if (k < 432) {
        int tap = k / 48, ci = k - tap * 48;
        int co = n16 * 16 + col;
        v = f2bf(w[((size_t)co * 48 + ci) * 9 + tap]);
    }
    Wp[idx] = v;
}

// ---- conv_up as bf16 MFMA GEMM: M=8192 px, N=768 co, K=448; pixel-shuffle bf16 write ----
__global__ __launch_bounds__(256) void conv_up_mfma_kernel(const short* __restrict__ hbfp,
                                                           const short* __restrict__ Wp,
                                                           const float* __restrict__ bias,
                                                           short* __restrict__ U) {
    int tid = threadIdx.x;
    int wave = tid >> 6, lane = tid & 63;
    int t = blockIdx.x * 4 + wave;          // 24576 tiles
    int mt = t / 48;
    int n16 = t - mt * 48;
    int b = mt >> 8;
    int rem = mt & 255;
    int y = rem >> 2;
    int xt = rem & 3;
    int col = lane & 15;
    int g = lane >> 4;
    int x = xt * 16 + col;                  // A-row pixel x

    const short* Bp = Wp + (size_t)n16 * (14 * 512) + col * 32 + g * 8;
    const short* zb = hbfp + 2 * 66 * 66 * 48;   // 64 zero shorts

    f32x4 acc = {0.f, 0.f, 0.f, 0.f};
    #pragma unroll
    for (int s = 0; s < 14; s++) {
        int gg = 4 * s + g;
        int tap = (gg * 171) >> 10;         // gg/6 for gg<60
        int cig = gg - tap * 6;
        int dy = (tap * 11) >> 5;           // tap/3 for tap<9(+)
        int dx = tap - dy * 3;
        const short* ap = hbfp + ((size_t)((b * 66 + y + dy) * 66 + (x + dx)) * 48 + cig * 8);
        ap = (gg < 54) ? ap : zb;
        short8v av = *(const short8v*)ap;
        short8v bv = *(const short8v*)(Bp + s * 512);
        acc = __builtin_amdgcn_mfma_f32_16x16x32_bf16(av, bv, acc, 0, 0, 0);
    }

    int co = n16 * 16 + col;
    float bval = bias[co];
    int ic = co >> 4, dyq = (co >> 2) & 3, dxq = co & 3;
    short* Ur = U + ((size_t)(b * 48 + ic) * 256 + 4 * y + dyq) * 256 + dxq;
    #pragma unroll
    for (int j = 0; j < 4; j++) {
        int r = 4 * g + j;                  // C row = pixel-x offset (m89 mapping)
        Ur[4 * (xt * 16 + r)] = f2bf(acc[j] + bval);
    }
}

// ---- zero bf16 pad regions; plant bf16 1.0 in Vr's padded row dd==12 (sum-row trick) ----
__global__ void zero16_kernel(u64* __restrict__ p, int n) {
    int i = blockIdx.x * 256 + threadIdx.x;
    if (i >= n) return;
    u64 fill = 0ull;
    // short offset of this 8-short chunk, relative to Vr start (Q:1M + K:1M shorts before it)
    int rel = 8 * i - 2097152;
    if (rel >= 0 && rel < 524288 && (((rel >> 5) & 15) == 12))
        fill = 0x3F803F803F803F80ull;     // bf16 1.0 x4
    p[2 * i] = fill;
    p[2 * i + 1] = fill;
}

// ---- fused: LN1 (NCHW) -> ln1 rows + qkv matmul -> bf16 Q/K/Vr (16-tok tiles) ----
__global__ __launch_bounds__(256) void fused_ln1_qkv_kernel(
    const float* __restrict__ hsrc, const float* __restrict__ g1, const float* __restrict__ b1,
    const float* __restrict__ w, const float* __restrict__ bias,
    float* __restrict__ ln1, short* __restrict__ Qbf, short* __restrict__ Kbf,
    short* __restrict__ Vr) {
    __shared__ float hs[48 * 17];
    __shared__ float lnr[16 * 49];
    __shared__ float wl[48 * 144];
    int blk = blockIdx.x;
    int b = blk >> 8;
    int pos0 = (blk & 255) * 16;
    int tid = threadIdx.x;

    for (int i = tid; i < 48 * 144; i += 256) wl[i] = w[i];
    for (int i = tid; i < 48 * 16; i += 256) {
        int ch = i >> 4, p = i & 15;
        hs[ch * 17 + p] = hsrc[((size_t)b * 48 + ch) * 4096 + pos0 + p];
    }
    __syncthreads();

    int tok = tid >> 4, oct = tid & 15;
    int pos = pos0 + tok;
    float v[3];
    float s = 0.f, s2 = 0.f;
    #pragma unroll
    for (int j = 0; j < 3; j++) {
        float x = hs[(oct * 3 + j) * 17 + tok];
        v[j] = x; s += x; s2 += x * x;
    }
    #pragma unroll
    for (int msk = 1; msk < 16; msk <<= 1) {
        s += __shfl_xor(s, msk, 64);
        s2 += __shfl_xor(s2, msk, 64);
    }
    float mu = s * (1.f / 48.f);
    float var = s2 * (1.f / 48.f) - mu * mu;
    float rs = rsqrtf(var + 1e-5f);
    float* go = ln1 + ((size_t)b * 4096 + pos) * 48 + oct * 3;
    #pragma unroll
    for (int j = 0; j < 3; j++) {
        int c = oct * 3 + j;
        float y = (v[j] - mu) * rs * g1[c] + b1[c];
        lnr[tok * 49 + c] = y;
        go[j] = y;
    }
    __syncthreads();

    int c0 = oct * 9;
    float acc[9];
    #pragma unroll
    for (int j = 0; j < 9; j++) acc[j] = bias[c0 + j];
    #pragma unroll 4
    for (int k = 0; k < 48; k++) {
        float a = lnr[tok * 49 + k];
        const float* wr = wl + k * 144 + c0;
        #pragma unroll
        for (int j = 0; j < 9; j++) acc[j] += a * wr[j];
    }

    // 1/sqrt(12) * log2(e): softmax exp becomes a single raw v_exp_f32 (2^x)
    const float scale = 0.41647023f;
    int sstep = pos >> 5, r = pos & 31;
    int g2 = (r < 16) ? (r >> 2) : ((r - 16) >> 2);
    int j2 = (r < 16) ? (r & 3) : 4 + ((r - 16) & 3);
    #pragma unroll
    for (int j = 0; j < 9; j++) {
        int c = c0 + j;
        int which = (c >= 96) ? 2 : (c >= 48 ? 1 : 0);
        int rem = c - which * 48;
        int hh = rem / 12;
        int dd = rem - hh * 12;
        int bh = b * 4 + hh;
        if (which == 0)
            Qbf[((size_t)bh * 4096 + pos) * 32 + dd] = f2bf(acc[j] * scale);
        else if (which == 1)
            Kbf[((size_t)bh * 4096 + pos) * 32 + dd] = f2bf(acc[j]);
        else
            Vr[((size_t)bh * 128 + sstep) * 512 + dd * 32 + g2 * 8 + j2] = f2bf(acc[j]);
    }
}

// ---- fused: split-combine + proj + resid + LN2 + fc1 + GELU + fc2 + resid + h-accum ----
__global__ __launch_bounds__(256) void fused_mlp_kernel(
    const float* __restrict__ opart, const float* __restrict__ ssump,
    const float* __restrict__ pwg, const float* __restrict__ pb,
    const float* __restrict__ ln1, const float* __restrict__ g2v, const float* __restrict__ b2v,
    const float* __restrict__ f1w, const float* __restrict__ f1b,
    const float* __restrict__ f2w, const float* __restrict__ f2b,
    float* __restrict__ hbuf) {
    __shared__ float sm[14640];
    float* wp  = sm;            // 2304  (48x48 proj)
    float* w1  = sm + 2304;     // 4608  (48x96 fc1)
    float* w2  = sm + 6912;     // 4608  (96x48 fc2)
    float* arf = sm + 11520;    // 784   (16x49) attn rows, reused as fc2-out
    float* lnr = sm + 12304;    // 784   (16x49) ln2 rows
    float* m1v = sm + 13088;    // 1552  (16x97) gelu(fc1)

    int blk = blockIdx.x;
    int b = blk >> 8;
    int pos0 = (blk & 255) * 16;
    int tid = threadIdx.x;

    for (int i = tid; i < 2304; i += 256) wp[i] = pwg[i];
    for (int i = tid; i < 4608; i += 256) w1[i] = f1w[i];
    for (int i = tid; i < 4608; i += 256) w2[i] = f2w[i];
    // combine split partials -> normalized attention rows (per-thread, no extra sync deps)
    for (int i = tid; i < 768; i += 256) {
        int t = i / 48, c = i - (i / 48) * 48;
        int hh = c / 12;
        size_t base = ((size_t)b * 4096 + pos0) * 48 + i;
        float stot = 0.f, s = 0.f;
        #pragma unroll
        for (int sp = 0; sp < NSPLIT; sp++) {
            stot += ssump[((size_t)sp * 8 + b * 4 + hh) * 4096 + pos0 + t];
            s += opart[base + (size_t)sp * OPART_STRIDE];
        }
        arf[t * 49 + c] = s / stot;
    }
    __syncthreads();

    int tok = tid >> 4, oct = tid & 15;
    size_t gtok = (size_t)b * 4096 + pos0 + tok;
    int c0 = oct * 3;
    float acc[3];
    #pragma unroll
    for (int j = 0; j < 3; j++) acc[j] = pb[c0 + j];
    #pragma unroll 4
    for (int k = 0; k < 48; k++) {
        float a = arf[tok * 49 + k];
        const float* wr = wp + k * 48 + c0;
        #pragma unroll
        for (int j = 0; j < 3; j++) acc[j] += a * wr[j];
    }
    const float* rp = ln1 + gtok * 48 + c0;
    float x[3]; float s = 0.f, s2 = 0.f;
    #pragma unroll
    for (int j = 0; j < 3; j++) {
        float t = acc[j] + rp[j];
        x[j] = t; s += t; s2 += t * t;
    }
    #pragma unroll
    for (int msk = 1; msk < 16; msk <<= 1) {
        s += __shfl_xor(s, msk, 64);
        s2 += __shfl_xor(s2, msk, 64);
    }
    float mu = s * (1.f / 48.f), var = s2 * (1.f / 48.f) - mu * mu;
    float rs = rsqrtf(var + 1e-5f);
    #pragma unroll
    for (int j = 0; j < 3; j++) {
        int c = c0 + j;
        lnr[tok * 49 + c] = (x[j] - mu) * rs * g2v[c] + b2v[c];
    }
    __syncthreads();

    // fc1 + GELU -> m1v (LDS only)
    int d0 = oct * 6;
    float a2[6];
    #pragma unroll
    for (int j = 0; j < 6; j++) a2[j] = f1b[d0 + j];
    #pragma unroll 4
    for (int k = 0; k < 48; k++) {
        float a = lnr[tok * 49 + k];
        const float* wr = w1 + k * 96 + d0;
        #pragma unroll
        for (int j = 0; j < 6; j++) a2[j] += a * wr[j];
    }
    #pragma unroll
    for (int j = 0; j < 6; j++) {
        float g = a2[j];
        m1v[tok * 97 + d0 + j] = 0.5f * g * (1.f + erff(g * 0.70710678118654752f));
    }
    __syncthreads();

    // fc2 + ln2-residual -> arf (reused)
    float f2acc[3];
    #pragma unroll
    for (int j = 0; j < 3; j++) f2acc[j] = f2b[c0 + j];
    #pragma unroll 4
    for (int k = 0; k < 96; k++) {
        float a = m1v[tok * 97 + k];
        const float* wr = w2 + k * 48 + c0;
        #pragma unroll
        for (int j = 0; j < 3; j++) f2acc[j] += a * wr[j];
    }
    __syncthreads();
    #pragma unroll
    for (int j = 0; j < 3; j++)
        arf[tok * 49 + c0 + j] = f2acc[j] + lnr[tok * 49 + c0 + j];
    __syncthreads();

    // cooperative coalesced transposed accumulate into h (NCHW)
    for (int i = tid; i < 768; i += 256) {
        int c = i >> 4, t = i & 15;
        hbuf[(((size_t)(b * 48 + c)) << 12) + pos0 + t] += arf[t * 49 + c];
    }
}

// ---- MFMA flash attention: 32 q/wave (2 fragments sharing K/V loads), split-K x4,
//      128-key chunk double-buffer (R1-proven pipeline). No-max softmax: partials
//      (o, sum p) are plain sums -> additive combine in fused_mlp. Row sum via V
//      ones-row (dd==12). 2 frags halve per-dispatch L2 traffic (786 -> 393 MB).
#define LOADCH(P, c) { \
    _Pragma("unroll") \
    for (int s_ = 0; s_ < 4; s_++) { \
        const short* kp_ = Kb + ((size_t)((c) * 128 + s_ * 32 + col)) * 32 + g * 8; \
        P##k0[s_] = *(const short8v*)(kp_); \
        P##k1[s_] = *(const short8v*)(kp_ + 512); \
        P##v[s_]  = *(const short8v*)(Vrb + ((c) * 4 + s_) * 512 + vbase); \
    } }

#define STEP2(kc0, kc1, vv) { \
    f32x4 z_ = {0.f, 0.f, 0.f, 0.f}; \
    f32x4 sa1 = __builtin_amdgcn_mfma_f32_16x16x32_bf16(kc0, qb0, z_, 0, 0, 0); \
    f32x4 sa2 = __builtin_amdgcn_mfma_f32_16x16x32_bf16(kc1, qb0, z_, 0, 0, 0); \
    f32x4 sb1 = __builtin_amdgcn_mfma_f32_16x16x32_bf16(kc0, qb1, z_, 0, 0, 0); \
    f32x4 sb2 = __builtin_amdgcn_mfma_f32_16x16x32_bf16(kc1, qb1, z_, 0, 0, 0); \
    float a0 = exp2_raw(sa1[0]), a1 = exp2_raw(sa1[1]); \
    float a2 = exp2_raw(sa1[2]), a3 = exp2_raw(sa1[3]); \
    float a4 = exp2_raw(sa2[0]), a5 = exp2_raw(sa2[1]); \
    float a6 = exp2_raw(sa2[2]), a7 = exp2_raw(sa2[3]); \
    float e0 = exp2_raw(sb1[0]), e1 = exp2_raw(sb1[1]); \
    float e2 = exp2_raw(sb1[2]), e3 = exp2_raw(sb1[3]); \
    float e4 = exp2_raw(sb2[0]), e5 = exp2_raw(sb2[1]); \
    float e6 = exp2_raw(sb2[2]), e7 = exp2_raw(sb2[3]); \
    union { short8v sv; unsigned u[4]; } pa_, pe_; \
    asm("v_cvt_pk_bf16_f32 %0, %1, %2" : "=v"(pa_.u[0]) : "v"(a0), "v"(a1)); \
    asm("v_cvt_pk_bf16_f32 %0, %1, %2" : "=v"(pa_.u[1]) : "v"(a2), "v"(a3)); \
    asm("v_cvt_pk_bf16_f32 %0, %1, %2" : "=v"(pa_.u[2]) : "v"(a4), "v"(a5)); \
    asm("v_cvt_pk_bf16_f32 %0, %1, %2" : "=v"(pa_.u[3]) : "v"(a6), "v"(a7)); \
    asm("v_cvt_pk_bf16_f32 %0, %1, %2" : "=v"(pe_.u[0]) : "v"(e0), "v"(e1)); \
    asm("v_cvt_pk_bf16_f32 %0, %1, %2" : "=v"(pe_.u[1]) : "v"(e2), "v"(e3)); \
    asm("v_cvt_pk_bf16_f32 %0, %1, %2" : "=v"(pe_.u[2]) : "v"(e4), "v"(e5)); \
    asm("v_cvt_pk_bf16_f32 %0, %1, %2" : "=v"(pe_.u[3]) : "v"(e6), "v"(e7)); \
    o0 = __builtin_amdgcn_mfma_f32_16x16x32_bf16(vv, pa_.sv, o0, 0, 0, 0); \
    o1 = __builtin_amdgcn_mfma_f32_16x16x32_bf16(vv, pe_.sv, o1, 0, 0, 0); }

#define COMPUTECH2(P) { \
    STEP2(P##k0[0], P##k1[0], P##v[0]); \
    STEP2(P##k0[1], P##k1[1], P##v[1]); \
    STEP2(P##k0[2], P##k1[2], P##v[2]); \
    STEP2(P##k0[3], P##k1[3], P##v[3]); }

__global__ __launch_bounds__(256) void attn_mfma_kernel(const short* __restrict__ Qbf,
                                                        const short* __restrict__ Kbf,
                                                        const short* __restrict__ Vr,
                                                        float* __restrict__ opart,
                                                        float* __restrict__ ssump) {
    int bid = blockIdx.x;                 // split(4) | qblk(32) | bh(8) = 1024 blocks
    int bh = bid & 7;
    int qblk = (bid >> 3) & 31;
    int split = bid >> 8;
    int h = bh & 3, b = bh >> 2;
    int tid = threadIdx.x;
    int wave = tid >> 6;
    int lane = tid & 63;
    int q0 = qblk * 128 + wave * 32;      // 32 q per wave (2 x 16-q fragments)
    int col = lane & 15;
    int g = lane >> 4;

    const short* Kb  = Kbf + (size_t)bh * LL * 32 + (size_t)split * 1024 * 32;
    const short* Vrb = Vr + (size_t)bh * 65536 + (size_t)split * 32 * 512;
    int vbase = col * 32 + g * 8;

    short8v qb0 = *(const short8v*)(Qbf + ((size_t)bh * LL + q0 + col) * 32 + g * 8);
    short8v qb1 = *(const short8v*)(Qbf + ((size_t)bh * LL + q0 + 16 + col) * 32 + g * 8);

    f32x4 o0 = {0.f, 0.f, 0.f, 0.f};
    f32x4 o1 = {0.f, 0.f, 0.f, 0.f};

    short8v a_k0[4], a_k1[4], a_v[4];
    short8v b_k0[4], b_k1[4], b_v[4];

    LOADCH(a_, 0);
    for (int c = 0; c < 8; c += 2) {
        LOADCH(b_, c + 1);
        COMPUTECH2(a_);
        if (c + 2 < 8) LOADCH(a_, c + 2);
        COMPUTECH2(b_);
    }

    // row 12 of o (lane group g==3, j==0) holds this split's sum(p) via V's ones-row
    float ssa = __shfl(o0[0], 48 + col, 64);
    float ssb = __shfl(o1[0], 48 + col, 64);

    float* op = opart + (size_t)split * OPART_STRIDE
              + ((size_t)b * 4096 + q0 + col) * 48 + h * HD;
    #pragma unroll
    for (int j = 0; j < 4; j++) {
        int d = 4 * g + j;
        if (d < HD) {
            op[d] = o0[j];
            op[16 * 48 + d] = o1[j];
        }
    }
    if (lane < 16) {
        float* sp = ssump + ((size_t)split * 8 + bh) * 4096 + q0 + col;
        sp[0] = ssa;
        sp[16] = ssb;
    }
}

// ---- last conv: 3x3 over bf16 U, 4-row x 32-col tiles, stage-split dbuf, grid 1024 ----
#define LW2 36
__global__ __launch_bounds__(128) void lastconv_kernel(const short* __restrict__ U,
                                                       const float* __restrict__ w,
                                                       const float* __restrict__ bias,
                                                       float* __restrict__ out) {
    int blk = blockIdx.x;          // xt(8: 32-col), yt(64: 4-row), b(2) -> 1024 blocks
    int xt = blk & 7;
    int yt = (blk >> 3) & 63;
    int b = blk >> 9;
    int tid = threadIdx.x;
    int xx = tid & 31;
    int yy = tid >> 5;             // 0..3
    int y0 = yt * 4;
    int x0t = xt * 32;
    int y = y0 + yy;
    int x = x0t + xx;

    __shared__ float wl[3 * 48 * 9];
    __shared__ float tile[2][6 * LW2];
    for (int i = tid; i < 3 * 48 * 9; i += 128) wl[i] = w[i];

    const short* Ub = U + (size_t)b * 48 * 65536;

    // staging: 6 rows x 34 cols = 204 slots, 128 thr -> 2 chunks
    int soff[2]; int doff[2]; bool sval[2]; bool swr[2];
    #pragma unroll
    for (int kk = 0; kk < 2; kk++) {
        int i = tid + kk * 128;
        int r = i / 34, c = i - r * 34;
        int gy = y0 - 1 + r, gx = x0t - 1 + c;
        bool inb_ok = (i < 204);
        bool ok = inb_ok && (gy >= 0 && gy < 256 && gx >= 0 && gx < 256);
        swr[kk] = inb_ok;
        sval[kk] = ok;
        doff[kk] = inb_ok ? r * LW2 + c : 0;
        soff[kk] = ok ? gy * 256 + gx : 0;
    }

    {
        float* tb = tile[0];
        #pragma unroll
        for (int kk = 0; kk < 2; kk++)
            if (swr[kk]) tb[doff[kk]] = sval[kk] ? bf2f(Ub[soff[kk]]) : 0.f;
    }

    float acc[3];
    #pragma unroll
    for (int oc = 0; oc < 3; oc++) acc[oc] = bias[oc];
    __syncthreads();

    for (int ci = 0; ci < 48; ci++) {
        float rr[2];
        if (ci + 1 < 48) {
            const short* ip = Ub + (size_t)(ci + 1) * 65536;
            #pragma unroll
            for (int kk = 0; kk < 2; kk++)
                rr[kk] = sval[kk] ? bf2f(ip[soff[kk]]) : 0.f;
        }
        const float* tp = tile[ci & 1];
        float row[3][3];
        #pragma unroll
        for (int ky = 0; ky < 3; ky++) {
            const float* rp = tp + (yy + ky) * LW2 + xx;
            #pragma unroll
            for (int dx = 0; dx < 3; dx++) row[ky][dx] = rp[dx];
        }
        #pragma unroll
        for (int oc = 0; oc < 3; oc++) {
            const float* wp = wl + (oc * 48 + ci) * 9;
            acc[oc] += wp[0] * row[0][0] + wp[1] * row[0][1] + wp[2] * row[0][2]
                     + wp[3] * row[1][0] + wp[4] * row[1][1] + wp[5] * row[1][2]
                     + wp[6] * row[2][0] + wp[7] * row[2][1] + wp[8] * row[2][2];
        }
        if (ci + 1 < 48) {
            float* tb = tile[(ci + 1) & 1];
            #pragma unroll
            for (int kk = 0; kk < 2; kk++)
                if (swr[kk]) tb[doff[kk]] = rr[kk];
        }
        __syncthreads();
    }
    #pragma unroll
    for (int oc = 0; oc < 3; oc++)
        out[(((size_t)(b * 3 + oc) * 256) + y) * 256 + x] = acc[oc];
}

static inline int gs(int n) { return (n + 255) / 256; }

extern "C" void kernel_launch(void* const* d_in, const int* in_sizes, int n_in,
                              void* d_out, int out_size, void* d_ws, size_t ws_size,
                              hipStream_t stream) {
    const float* x    = (const float*)d_in[0];
    const float* cf_w = (const float*)d_in[1];
    const float* cf_b = (const float*)d_in[2];
    const float* n1g  = (const float*)d_in[3];
    const float* n1b  = (const float*)d_in[4];
    const float* qkvw = (const float*)d_in[5];
    const float* qkvb = (const float*)d_in[6];
    const float* pw   = (const float*)d_in[7];
    const float* pb   = (const float*)d_in[8];
    const float* n2g  = (const float*)d_in[9];
    const float* n2b  = (const float*)d_in[10];
    const float* f1w  = (const float*)d_in[11];
    const float* f1b  = (const float*)d_in[12];
    const float* f2w  = (const float*)d_in[13];
    const float* f2b  = (const float*)d_in[14];
    const float* upw  = (const float*)d_in[15];
    const float* upb  = (const float*)d_in[16];
    const float* lw   = (const float*)d_in[17];
    const float* lb   = (const float*)d_in[18];

    float* ws = (float*)d_ws;
    const int S_h = BB * D * LL;            // 393216
    float* A_h   = ws;
    float* pool  = ws + S_h;
    float* A_ln1 = pool;

    // U now bf16: [b][48][256][256] shorts = 3145728 floats-worth at pool[0]
    short* U_bf = (short*)pool;
    // attention split partials: o_part [4][B*L*48] in the old A_att slot + free gap
    float* o_part = pool + 1572864;                    // 4*393216 = 1572864 floats, ends 3145728
    // packs live between o_part end and Qbf start
    short* hbfp = (short*)(pool + 3145728);            // 418240 shorts (incl. 64 zero pad)
    short* Wp   = (short*)(pool + 3145728 + 209120);   // 344064 shorts
    short* Qbf  = (short*)(pool + 3538944);
    short* Kbf  = Qbf + BB * NHEADS * LL * 32;
    short* Vr   = Kbf + BB * NHEADS * LL * 32;
    // ssum partials after Vr end (pool+5898240), 4*8*4096 = 131072 floats < old footprint
    float* ssum_part = pool + 5898240;

    // conv_first (3 -> 48)
    conv3x3_kernel<<<gs(S_h), 256, 0, stream>>>(x, cf_w, cf_b, A_h, 3, D);

    // zero Q/K/Vr (pads must be 0; Vr ones-row planted; real entries overwritten every block)
    zero16_kernel<<<1536, 256, 0, stream>>>((u64*)Qbf, 393216);
    // pack conv_up weights (input-only dependency)
    pack_w_kernel<<<1344, 256, 0, stream>>>(upw, Wp);

    for (int i = 0; i < NBLK; i++) {
        fused_ln1_qkv_kernel<<<512, 256, 0, stream>>>(
            A_h, n1g + i * D, n1b + i * D,
            qkvw + (size_t)i * D * 3 * D, qkvb + i * 3 * D,
            A_ln1, Qbf, Kbf, Vr);
        attn_mfma_kernel<<<8 * 32 * NSPLIT, 256, 0, stream>>>(Qbf, Kbf, Vr, o_part, ssum_part);
        fused_mlp_kernel<<<512, 256, 0, stream>>>(
            o_part, ssum_part, pw + (size_t)i * D * D, pb + i * D,
            A_ln1, n2g + i * D, n2b + i * D,
            f1w + (size_t)i * D * 2 * D, f1b + i * 2 * D,
            f2w + (size_t)i * 2 * D * D, f2b + i * D,
            A_h);
    }

    // pack h -> bf16 halo'd channel-last, then MFMA GEMM conv_up (+pixel shuffle, bf16 U)
    pack_h_kernel<<<1634, 256, 0, stream>>>(A_h, hbfp);
    conv_up_mfma_kernel<<<6144, 256, 0, stream>>>(hbfp, Wp, upb, U_bf);

    // last conv: plain 3x3 over bf16 U -> f32 out
    lastconv_kernel<<<1024, 128, 0, stream>>>(U_bf, lw, lb, (float*)d_out);
}

// Round 5
// 309.999 us; speedup vs baseline: 1.2870x; 1.0407x over previous
//
#include <hip/hip_runtime.h>
#include <hip/hip_bf16.h>
#include <math.h>

#define BB 2
#define D 48
#define HH 64
#define WW 64
#define LL 4096      // HH*WW
#define NHEADS 4
#define HD 12
#define NBLK 4
#define CUP 768
#define H2 256
#define W2 256

#define NSPLIT 4
#define OPART_STRIDE 393216   // B*L*48 floats per split

typedef __attribute__((ext_vector_type(8))) short short8v;
typedef __attribute__((ext_vector_type(4))) float f32x4;
typedef unsigned long long u64;

__device__ __forceinline__ short f2bf(float f) {
    __hip_bfloat16 h = __float2bfloat16(f);
    union { __hip_bfloat16 b; short s; } u; u.b = h; return u.s;
}
__device__ __forceinline__ float bf2f(short s) {
    union { float f; unsigned u; } x;
    x.u = ((unsigned)(unsigned short)s) << 16;
    return x.f;
}
// raw 2^x (hardware approx, ~1 ulp; inputs are tiny softmax scores -> safe)
__device__ __forceinline__ float exp2_raw(float x) {
    float r; asm("v_exp_f32 %0, %1" : "=v"(r) : "v"(x)); return r;
}

// ---------------- generic 3x3 SAME conv, f32 (used for conv_first only) ----------------
__global__ void conv3x3_kernel(const float* __restrict__ in, const float* __restrict__ w,
                               const float* __restrict__ bias, float* __restrict__ out,
                               int Cin, int Cout) {
    int idx = blockIdx.x * blockDim.x + threadIdx.x;
    int total = BB * Cout * HH * WW;
    if (idx >= total) return;
    int x = idx % WW;
    int y = (idx / WW) % HH;
    int co = (idx / (WW * HH)) % Cout;
    int b = idx / (WW * HH * Cout);
    float s = bias[co];
    for (int ci = 0; ci < Cin; ci++) {
        const float* ip = in + ((size_t)(b * Cin + ci) * HH) * WW;
        const float* wp = w + (size_t)(co * Cin + ci) * 9;
        #pragma unroll
        for (int ky = 0; ky < 3; ky++) {
            int iy = y + ky - 1;
            if (iy < 0 || iy >= HH) continue;
            #pragma unroll
            for (int kx = 0; kx < 3; kx++) {
                int ix = x + kx - 1;
                if (ix < 0 || ix >= WW) continue;
                s += ip[iy * WW + ix] * wp[ky * 3 + kx];
            }
        }
    }
    out[idx] = s;
}

// ---- pack h (NCHW f32) -> bf16 channel-last with 1-px zero halo: [b][66][66][48] + 64 zero ----
__global__ __launch_bounds__(256) void pack_h_kernel(const float* __restrict__ h,
                                                     short* __restrict__ hbfp) {
    int idx = blockIdx.x * 256 + threadIdx.x;
    const int TOT = 2 * 66 * 66 * 48;    // 418176
    if (idx >= TOT + 64) return;
    if (idx >= TOT) { hbfp[idx] = 0; return; }
    int ci = idx % 48;
    int p = idx / 48;
    int xx = p % 66;
    int q = p / 66;
    int yy = q % 66;
    int b = q / 66;
    short v = 0;
    if (yy >= 1 && yy <= 64 && xx >= 1 && xx <= 64)
        v = f2bf(h[((size_t)(b * 48 + ci) << 12) + (yy - 1) * 64 + (xx - 1)]);
    hbfp[idx] = v;
}

// ---- pack conv_up weights into B-fragment order: Wp[n16][s][col][g][j], K=tap*48+ci pad 448 ----
__global__ __launch_bounds__(256) void pack_w_kernel(const float* __restrict__ w,
                                                     short* __restrict__ Wp) {
    int idx = blockIdx.x * 256 + threadIdx.x;
    if (idx >= 48 * 14 * 512) return;    // 344064
    int j = idx & 7;
    int g = (idx >> 3) & 3;
    int col = (idx >> 5) & 15;
    int s = (idx >> 9) % 14;
    int n16 = idx / (14 * 512);
    int k = 32 * s + 8 * g + j;
    short v = 0;
    if (k < 432) {
        int tap = k / 48, ci = k - tap * 48;
        int co = n16 * 16 + col;
        v = f2bf(w[((size_t)co * 48 + ci) * 9 + tap]);
    }
    Wp[idx] = v;
}

// ---- pack last-conv weights into B-fragment order: Wp2[s][col][g][j], cols 3..15 zero ----
__global__ __launch_bounds__(256) void pack_lw_kernel(const float* __restrict__ w,
                                                      short* __restrict__ Wp2) {
    int idx = blockIdx.x * 256 + threadIdx.x;
    if (idx >= 14 * 512) return;         // 7168
    int j = idx & 7;
    int g = (idx >> 3) & 3;
    int col = (idx >> 5) & 15;
    int s = idx >> 9;
    int k = 32 * s + 8 * g + j;
    short v = 0;
    if (k < 432 && col < 3) {
        int tap = k / 48, ci = k - tap * 48;
        v = f2bf(w[((size_t)col * 48 + ci) * 9 + tap]);
    }
    Wp2[idx] = v;
}

// ---- conv_up as bf16 MFMA GEMM: M=8192 px, N=768 co, K=448; pixel-shuffle write ----
// U is CHANNEL-LAST: [b][256][256][48] bf16 (consumed by lastconv_mfma's im2col reads)
__global__ __launch_bounds__(256) void conv_up_mfma_kernel(const short* __restrict__ hbfp,
                                                           const short* __restrict__ Wp,
                                                           const float* __restrict__ bias,
                                                           short* __restrict__ U) {
    int tid = threadIdx.x;
    int wave = tid >> 6, lane = tid & 63;
    int t = blockIdx.x * 4 + wave;          // 24576 tiles
    int mt = t / 48;
    int n16 = t - mt * 48;
    int b = mt >> 8;
    int rem = mt & 255;
    int y = rem >> 2;
    int xt = rem & 3;
    int col = lane & 15;
    int g = lane >> 4;
    int x = xt * 16 + col;                  // A-row pixel x

    const short* Bp = Wp + (size_t)n16 * (14 * 512) + col * 32 + g * 8;
    const short* zb = hbfp + 2 * 66 * 66 * 48;   // 64 zero shorts

    f32x4 acc = {0.f, 0.f, 0.f, 0.f};
    #pragma unroll
    for (int s = 0; s < 14; s++) {
        int gg = 4 * s + g;
        int tap = (gg * 171) >> 10;         // gg/6 for gg<60
        int cig = gg - tap * 6;
        int dy = (tap * 11) >> 5;           // tap/3 for tap<9(+)
        int dx = tap - dy * 3;
        const short* ap = hbfp + ((size_t)((b * 66 + y + dy) * 66 + (x + dx)) * 48 + cig * 8);
        ap = (gg < 54) ? ap : zb;
        short8v av = *(const short8v*)ap;
        short8v bv = *(const short8v*)(Bp + s * 512);
        acc = __builtin_amdgcn_mfma_f32_16x16x32_bf16(av, bv, acc, 0, 0, 0);
    }

    int co = n16 * 16 + col;
    float bval = bias[co];
    int ic = co >> 4, dyq = (co >> 2) & 3, dxq = co & 3;
    int y2 = 4 * y + dyq;
    short* Ur = U + ((size_t)(b * 256 + y2) * 256) * 48 + ic;
    #pragma unroll
    for (int j = 0; j < 4; j++) {
        int r = 4 * g + j;                  // C row = pixel-x offset (m89 mapping)
        int x2 = 4 * (xt * 16 + r) + dxq;
        Ur[(size_t)x2 * 48] = f2bf(acc[j] + bval);
    }
}

// ---- zero bf16 pad regions; plant bf16 1.0 in Vr's padded row dd==12 (sum-row trick) ----
__global__ void zero16_kernel(u64* __restrict__ p, int n) {
    int i = blockIdx.x * 256 + threadIdx.x;
    if (i >= n) return;
    u64 fill = 0ull;
    // short offset of this 8-short chunk, relative to Vr start (Q:1M + K:1M shorts before it)
    int rel = 8 * i - 2097152;
    if (rel >= 0 && rel < 524288 && (((rel >> 5) & 15) == 12))
        fill = 0x3F803F803F803F80ull;     // bf16 1.0 x4
    p[2 * i] = fill;
    p[2 * i + 1] = fill;
}

// ---- fused: LN1 (NCHW) -> ln1 rows + qkv matmul -> bf16 Q/K/Vr (16-tok tiles) ----
__global__ __launch_bounds__(256) void fused_ln1_qkv_kernel(
    const float* __restrict__ hsrc, const float* __restrict__ g1, const float* __restrict__ b1,
    const float* __restrict__ w, const float* __restrict__ bias,
    float* __restrict__ ln1, short* __restrict__ Qbf, short* __restrict__ Kbf,
    short* __restrict__ Vr) {
    __shared__ float hs[48 * 17];
    __shared__ float lnr[16 * 49];
    __shared__ float wl[48 * 144];
    int blk = blockIdx.x;
    int b = blk >> 8;
    int pos0 = (blk & 255) * 16;
    int tid = threadIdx.x;

    for (int i = tid; i < 48 * 144; i += 256) wl[i] = w[i];
    for (int i = tid; i < 48 * 16; i += 256) {
        int ch = i >> 4, p = i & 15;
        hs[ch * 17 + p] = hsrc[((size_t)b * 48 + ch) * 4096 + pos0 + p];
    }
    __syncthreads();

    int tok = tid >> 4, oct = tid & 15;
    int pos = pos0 + tok;
    float v[3];
    float s = 0.f, s2 = 0.f;
    #pragma unroll
    for (int j = 0; j < 3; j++) {
        float x = hs[(oct * 3 + j) * 17 + tok];
        v[j] = x; s += x; s2 += x * x;
    }
    #pragma unroll
    for (int msk = 1; msk < 16; msk <<= 1) {
        s += __shfl_xor(s, msk, 64);
        s2 += __shfl_xor(s2, msk, 64);
    }
    float mu = s * (1.f / 48.f);
    float var = s2 * (1.f / 48.f) - mu * mu;
    float rs = rsqrtf(var + 1e-5f);
    float* go = ln1 + ((size_t)b * 4096 + pos) * 48 + oct * 3;
    #pragma unroll
    for (int j = 0; j < 3; j++) {
        int c = oct * 3 + j;
        float y = (v[j] - mu) * rs * g1[c] + b1[c];
        lnr[tok * 49 + c] = y;
        go[j] = y;
    }
    __syncthreads();

    int c0 = oct * 9;
    float acc[9];
    #pragma unroll
    for (int j = 0; j < 9; j++) acc[j] = bias[c0 + j];
    #pragma unroll 4
    for (int k = 0; k < 48; k++) {
        float a = lnr[tok * 49 + k];
        const float* wr = wl + k * 144 + c0;
        #pragma unroll
        for (int j = 0; j < 9; j++) acc[j] += a * wr[j];
    }

    // 1/sqrt(12) * log2(e): softmax exp becomes a single raw v_exp_f32 (2^x)
    const float scale = 0.41647023f;
    int sstep = pos >> 5, r = pos & 31;
    int g2 = (r < 16) ? (r >> 2) : ((r - 16) >> 2);
    int j2 = (r < 16) ? (r & 3) : 4 + ((r - 16) & 3);
    #pragma unroll
    for (int j = 0; j < 9; j++) {
        int c = c0 + j;
        int which = (c >= 96) ? 2 : (c >= 48 ? 1 : 0);
        int rem = c - which * 48;
        int hh = rem / 12;
        int dd = rem - hh * 12;
        int bh = b * 4 + hh;
        if (which == 0)
            Qbf[((size_t)bh * 4096 + pos) * 32 + dd] = f2bf(acc[j] * scale);
        else if (which == 1)
            Kbf[((size_t)bh * 4096 + pos) * 32 + dd] = f2bf(acc[j]);
        else
            Vr[((size_t)bh * 128 + sstep) * 512 + dd * 32 + g2 * 8 + j2] = f2bf(acc[j]);
    }
}

// ---- fused: split-combine + proj + resid + LN2 + fc1 + GELU + fc2 + resid + h-accum ----
__global__ __launch_bounds__(256) void fused_mlp_kernel(
    const float* __restrict__ opart, const float* __restrict__ ssump,
    const float* __restrict__ pwg, const float* __restrict__ pb,
    const float* __restrict__ ln1, const float* __restrict__ g2v, const float* __restrict__ b2v,
    const float* __restrict__ f1w, const float* __restrict__ f1b,
    const float* __restrict__ f2w, const float* __restrict__ f2b,
    float* __restrict__ hbuf) {
    __shared__ float sm[14640];
    float* wp  = sm;            // 2304  (48x48 proj)
    float* w1  = sm + 2304;     // 4608  (48x96 fc1)
    float* w2  = sm + 6912;     // 4608  (96x48 fc2)
    float* arf = sm + 11520;    // 784   (16x49) attn rows, reused as fc2-out
    float* lnr = sm + 12304;    // 784   (16x49) ln2 rows
    float* m1v = sm + 13088;    // 1552  (16x97) gelu(fc1)

    int blk = blockIdx.x;
    int b = blk >> 8;
    int pos0 = (blk & 255) * 16;
    int tid = threadIdx.x;

    for (int i = tid; i < 2304; i += 256) wp[i] = pwg[i];
    for (int i = tid; i < 4608; i += 256) w1[i] = f1w[i];
    for (int i = tid; i < 4608; i += 256) w2[i] = f2w[i];
    // combine split partials -> normalized attention rows (per-thread, no extra sync deps)
    for (int i = tid; i < 768; i += 256) {
        int t = i / 48, c = i - (i / 48) * 48;
        int hh = c / 12;
        size_t base = ((size_t)b * 4096 + pos0) * 48 + i;
        float stot = 0.f, s = 0.f;
        #pragma unroll
        for (int sp = 0; sp < NSPLIT; sp++) {
            stot += ssump[((size_t)sp * 8 + b * 4 + hh) * 4096 + pos0 + t];
            s += opart[base + (size_t)sp * OPART_STRIDE];
        }
        arf[t * 49 + c] = s / stot;
    }
    __syncthreads();

    int tok = tid >> 4, oct = tid & 15;
    size_t gtok = (size_t)b * 4096 + pos0 + tok;
    int c0 = oct * 3;
    float acc[3];
    #pragma unroll
    for (int j = 0; j < 3; j++) acc[j] = pb[c0 + j];
    #pragma unroll 4
    for (int k = 0; k < 48; k++) {
        float a = arf[tok * 49 + k];
        const float* wr = wp + k * 48 + c0;
        #pragma unroll
        for (int j = 0; j < 3; j++) acc[j] += a * wr[j];
    }
    const float* rp = ln1 + gtok * 48 + c0;
    float x[3]; float s = 0.f, s2 = 0.f;
    #pragma unroll
    for (int j = 0; j < 3; j++) {
        float t = acc[j] + rp[j];
        x[j] = t; s += t; s2 += t * t;
    }
    #pragma unroll
    for (int msk = 1; msk < 16; msk <<= 1) {
        s += __shfl_xor(s, msk, 64);
        s2 += __shfl_xor(s2, msk, 64);
    }
    float mu = s * (1.f / 48.f), var = s2 * (1.f / 48.f) - mu * mu;
    float rs = rsqrtf(var + 1e-5f);
    #pragma unroll
    for (int j = 0; j < 3; j++) {
        int c = c0 + j;
        lnr[tok * 49 + c] = (x[j] - mu) * rs * g2v[c] + b2v[c];
    }
    __syncthreads();

    // fc1 + GELU -> m1v (LDS only)
    int d0 = oct * 6;
    float a2[6];
    #pragma unroll
    for (int j = 0; j < 6; j++) a2[j] = f1b[d0 + j];
    #pragma unroll 4
    for (int k = 0; k < 48; k++) {
        float a = lnr[tok * 49 + k];
        const float* wr = w1 + k * 96 + d0;
        #pragma unroll
        for (int j = 0; j < 6; j++) a2[j] += a * wr[j];
    }
    #pragma unroll
    for (int j = 0; j < 6; j++) {
        float g = a2[j];
        m1v[tok * 97 + d0 + j] = 0.5f * g * (1.f + erff(g * 0.70710678118654752f));
    }
    __syncthreads();

    // fc2 + ln2-residual -> arf (reused)
    float f2acc[3];
    #pragma unroll
    for (int j = 0; j < 3; j++) f2acc[j] = f2b[c0 + j];
    #pragma unroll 4
    for (int k = 0; k < 96; k++) {
        float a = m1v[tok * 97 + k];
        const float* wr = w2 + k * 48 + c0;
        #pragma unroll
        for (int j = 0; j < 3; j++) f2acc[j] += a * wr[j];
    }
    __syncthreads();
    #pragma unroll
    for (int j = 0; j < 3; j++)
        arf[tok * 49 + c0 + j] = f2acc[j] + lnr[tok * 49 + c0 + j];
    __syncthreads();

    // cooperative coalesced transposed accumulate into h (NCHW)
    for (int i = tid; i < 768; i += 256) {
        int c = i >> 4, t = i & 15;
        hbuf[(((size_t)(b * 48 + c)) << 12) + pos0 + t] += arf[t * 49 + c];
    }
}

// ---- MFMA flash attention: 32 q/wave (2 fragments sharing K/V loads), split-K x4,
//      128-key chunk double-buffer (R1-proven pipeline). No-max softmax: partials
//      (o, sum p) are plain sums -> additive combine in fused_mlp. Row sum via V
//      ones-row (dd==12). 2 frags halve per-dispatch L2 traffic (786 -> 393 MB).
#define LOADCH(P, c) { \
    _Pragma("unroll") \
    for (int s_ = 0; s_ < 4; s_++) { \
        const short* kp_ = Kb + ((size_t)((c) * 128 + s_ * 32 + col)) * 32 + g * 8; \
        P##k0[s_] = *(const short8v*)(kp_); \
        P##k1[s_] = *(const short8v*)(kp_ + 512); \
        P##v[s_]  = *(const short8v*)(Vrb + ((c) * 4 + s_) * 512 + vbase); \
    } }

#define STEP2(kc0, kc1, vv) { \
    f32x4 z_ = {0.f, 0.f, 0.f, 0.f}; \
    f32x4 sa1 = __builtin_amdgcn_mfma_f32_16x16x32_bf16(kc0, qb0, z_, 0, 0, 0); \
    f32x4 sa2 = __builtin_amdgcn_mfma_f32_16x16x32_bf16(kc1, qb0, z_, 0, 0, 0); \
    f32x4 sb1 = __builtin_amdgcn_mfma_f32_16x16x32_bf16(kc0, qb1, z_, 0, 0, 0); \
    f32x4 sb2 = __builtin_amdgcn_mfma_f32_16x16x32_bf16(kc1, qb1, z_, 0, 0, 0); \
    float a0 = exp2_raw(sa1[0]), a1 = exp2_raw(sa1[1]); \
    float a2 = exp2_raw(sa1[2]), a3 = exp2_raw(sa1[3]); \
    float a4 = exp2_raw(sa2[0]), a5 = exp2_raw(sa2[1]); \
    float a6 = exp2_raw(sa2[2]), a7 = exp2_raw(sa2[3]); \
    float e0 = exp2_raw(sb1[0]), e1 = exp2_raw(sb1[1]); \
    float e2 = exp2_raw(sb1[2]), e3 = exp2_raw(sb1[3]); \
    float e4 = exp2_raw(sb2[0]), e5 = exp2_raw(sb2[1]); \
    float e6 = exp2_raw(sb2[2]), e7 = exp2_raw(sb2[3]); \
    union { short8v sv; unsigned u[4]; } pa_, pe_; \
    asm("v_cvt_pk_bf16_f32 %0, %1, %2" : "=v"(pa_.u[0]) : "v"(a0), "v"(a1)); \
    asm("v_cvt_pk_bf16_f32 %0, %1, %2" : "=v"(pa_.u[1]) : "v"(a2), "v"(a3)); \
    asm("v_cvt_pk_bf16_f32 %0, %1, %2" : "=v"(pa_.u[2]) : "v"(a4), "v"(a5)); \
    asm("v_cvt_pk_bf16_f32 %0, %1, %2" : "=v"(pa_.u[3]) : "v"(a6), "v"(a7)); \
    asm("v_cvt_pk_bf16_f32 %0, %1, %2" : "=v"(pe_.u[0]) : "v"(e0), "v"(e1)); \
    asm("v_cvt_pk_bf16_f32 %0, %1, %2" : "=v"(pe_.u[1]) : "v"(e2), "v"(e3)); \
    asm("v_cvt_pk_bf16_f32 %0, %1, %2" : "=v"(pe_.u[2]) : "v"(e4), "v"(e5)); \
    asm("v_cvt_pk_bf16_f32 %0, %1, %2" : "=v"(pe_.u[3]) : "v"(e6), "v"(e7)); \
    o0 = __builtin_amdgcn_mfma_f32_16x16x32_bf16(vv, pa_.sv, o0, 0, 0, 0); \
    o1 = __builtin_amdgcn_mfma_f32_16x16x32_bf16(vv, pe_.sv, o1, 0, 0, 0); }

#define COMPUTECH2(P) { \
    STEP2(P##k0[0], P##k1[0], P##v[0]); \
    STEP2(P##k0[1], P##k1[1], P##v[1]); \
    STEP2(P##k0[2], P##k1[2], P##v[2]); \
    STEP2(P##k0[3], P##k1[3], P##v[3]); }

__global__ __launch_bounds__(256) void attn_mfma_kernel(const short* __restrict__ Qbf,
                                                        const short* __restrict__ Kbf,
                                                        const short* __restrict__ Vr,
                                                        float* __restrict__ opart,
                                                        float* __restrict__ ssump) {
    int bid = blockIdx.x;                 // split(4) | qblk(32) | bh(8) = 1024 blocks
    int bh = bid & 7;
    int qblk = (bid >> 3) & 31;
    int split = bid >> 8;
    int h = bh & 3, b = bh >> 2;
    int tid = threadIdx.x;
    int wave = tid >> 6;
    int lane = tid & 63;
    int q0 = qblk * 128 + wave * 32;      // 32 q per wave (2 x 16-q fragments)
    int col = lane & 15;
    int g = lane >> 4;

    const short* Kb  = Kbf + (size_t)bh * LL * 32 + (size_t)split * 1024 * 32;
    const short* Vrb = Vr + (size_t)bh * 65536 + (size_t)split * 32 * 512;
    int vbase = col * 32 + g * 8;

    short8v qb0 = *(const short8v*)(Qbf + ((size_t)bh * LL + q0 + col) * 32 + g * 8);
    short8v qb1 = *(const short8v*)(Qbf + ((size_t)bh * LL + q0 + 16 + col) * 32 + g * 8);

    f32x4 o0 = {0.f, 0.f, 0.f, 0.f};
    f32x4 o1 = {0.f, 0.f, 0.f, 0.f};

    short8v a_k0[4], a_k1[4], a_v[4];
    short8v b_k0[4], b_k1[4], b_v[4];

    LOADCH(a_, 0);
    for (int c = 0; c < 8; c += 2) {
        LOADCH(b_, c + 1);
        COMPUTECH2(a_);
        if (c + 2 < 8) LOADCH(a_, c + 2);
        COMPUTECH2(b_);
    }

    // row 12 of o (lane group g==3, j==0) holds this split's sum(p) via V's ones-row
    float ssa = __shfl(o0[0], 48 + col, 64);
    float ssb = __shfl(o1[0], 48 + col, 64);

    float* op = opart + (size_t)split * OPART_STRIDE
              + ((size_t)b * 4096 + q0 + col) * 48 + h * HD;
    #pragma unroll
    for (int j = 0; j < 4; j++) {
        int d = 4 * g + j;
        if (d < HD) {
            op[d] = o0[j];
            op[16 * 48 + d] = o1[j];
        }
    }
    if (lane < 16) {
        float* sp = ssump + ((size_t)split * 8 + bh) * 4096 + q0 + col;
        sp[0] = ssa;
        sp[16] = ssb;
    }
}

// ---- last conv as bf16 MFMA GEMM over channel-last U: M=131072 px, N=16 (3 real oc),
//      K=448 (tap*48+ci). Per-wave 16-px tile, 14 MFMAs, no LDS, no syncs. Boundary
//      taps resolved by zero-block pointer select (same idiom as conv_up's gg<54). ----
__global__ __launch_bounds__(256) void lastconv_mfma_kernel(const short* __restrict__ U,
                                                            const short* __restrict__ Wp2,
                                                            const short* __restrict__ zb,
                                                            const float* __restrict__ bias,
                                                            float* __restrict__ out) {
    int tid = threadIdx.x;
    int wave = tid >> 6, lane = tid & 63;
    int t = blockIdx.x * 4 + wave;        // 8192 tiles: b(2) | y(256) | xt(16)
    int xt = t & 15;
    int yy = (t >> 4) & 255;
    int b = t >> 12;
    int col = lane & 15, g = lane >> 4;
    int x = xt * 16 + col;                // A-row pixel x

    const short* Ub = U + (size_t)b * 65536 * 48;
    const short* Bp = Wp2 + col * 32 + g * 8;

    f32x4 acc = {0.f, 0.f, 0.f, 0.f};
    #pragma unroll
    for (int s = 0; s < 14; s++) {
        int gg = 4 * s + g;
        int tap = (gg * 171) >> 10;       // gg/6 for gg<60
        int cig = gg - tap * 6;
        int dy3 = (tap * 11) >> 5;        // tap/3 for tap<9(+)
        int dy = dy3 - 1;
        int dx = tap - dy3 * 3 - 1;
        int yq = yy + dy, xq = x + dx;
        bool ok = (gg < 54) && (yq >= 0) && (yq < 256) && (xq >= 0) && (xq < 256);
        const short* ap = Ub + (ptrdiff_t)(yq * 256 + xq) * 48 + cig * 8;
        ap = ok ? ap : zb;
        short8v av = *(const short8v*)ap;
        short8v bv = *(const short8v*)(Bp + s * 512);
        acc = __builtin_amdgcn_mfma_f32_16x16x32_bf16(av, bv, acc, 0, 0, 0);
    }

    if (col < 3) {
        float bval = bias[col];
        float* op = out + ((size_t)(b * 3 + col) * 256 + yy) * 256 + xt * 16 + 4 * g;
        #pragma unroll
        for (int j = 0; j < 4; j++)
            op[j] = acc[j] + bval;        // C row r=4g+j = pixel-x offset (m89 mapping)
    }
}

static inline int gs(int n) { return (n + 255) / 256; }

extern "C" void kernel_launch(void* const* d_in, const int* in_sizes, int n_in,
                              void* d_out, int out_size, void* d_ws, size_t ws_size,
                              hipStream_t stream) {
    const float* x    = (const float*)d_in[0];
    const float* cf_w = (const float*)d_in[1];
    const float* cf_b = (const float*)d_in[2];
    const float* n1g  = (const float*)d_in[3];
    const float* n1b  = (const float*)d_in[4];
    const float* qkvw = (const float*)d_in[5];
    const float* qkvb = (const float*)d_in[6];
    const float* pw   = (const float*)d_in[7];
    const float* pb   = (const float*)d_in[8];
    const float* n2g  = (const float*)d_in[9];
    const float* n2b  = (const float*)d_in[10];
    const float* f1w  = (const float*)d_in[11];
    const float* f1b  = (const float*)d_in[12];
    const float* f2w  = (const float*)d_in[13];
    const float* f2b  = (const float*)d_in[14];
    const float* upw  = (const float*)d_in[15];
    const float* upb  = (const float*)d_in[16];
    const float* lw   = (const float*)d_in[17];
    const float* lb   = (const float*)d_in[18];

    float* ws = (float*)d_ws;
    const int S_h = BB * D * LL;            // 393216
    float* A_h   = ws;
    float* pool  = ws + S_h;
    float* A_ln1 = pool;

    // U channel-last bf16: [b][256][256][48] shorts = 6291456 shorts = 3145728 floats at pool[0]
    // (written after the block loop; aliases A_ln1 + o_part, both dead by then)
    short* U_bf = (short*)pool;
    // attention split partials: o_part [4][B*L*48]
    float* o_part = pool + 1572864;                    // ends 3145728
    short* Qbf  = (short*)(pool + 3538944);
    short* Kbf  = Qbf + BB * NHEADS * LL * 32;         // +1048576 shorts
    short* Vr   = Kbf + BB * NHEADS * LL * 32;         // ends pool+4849664 floats
    // packs live in the dead gap after Vr (proven R3/R4 footprint, no growth)
    short* hbfp = (short*)(pool + 4849664);            // 418240 shorts -> ends 5058784
    short* Wp   = (short*)(pool + 5058784);            // 344064 shorts -> ends 5230816
    short* Wp2  = (short*)(pool + 5230816);            // 7168 shorts   -> ends 5234400
    // ssum partials
    float* ssum_part = pool + 5898240;                 // 131072 floats -> ends 6029312

    // conv_first (3 -> 48)
    conv3x3_kernel<<<gs(S_h), 256, 0, stream>>>(x, cf_w, cf_b, A_h, 3, D);

    // zero Q/K/Vr (pads must be 0; Vr ones-row planted; real entries overwritten every block)
    zero16_kernel<<<1536, 256, 0, stream>>>((u64*)Qbf, 393216);
    // pack conv_up + last-conv weights (input-only dependencies)
    pack_w_kernel<<<1344, 256, 0, stream>>>(upw, Wp);
    pack_lw_kernel<<<28, 256, 0, stream>>>(lw, Wp2);

    for (int i = 0; i < NBLK; i++) {
        fused_ln1_qkv_kernel<<<512, 256, 0, stream>>>(
            A_h, n1g + i * D, n1b + i * D,
            qkvw + (size_t)i * D * 3 * D, qkvb + i * 3 * D,
            A_ln1, Qbf, Kbf, Vr);
        attn_mfma_kernel<<<8 * 32 * NSPLIT, 256, 0, stream>>>(Qbf, Kbf, Vr, o_part, ssum_part);
        fused_mlp_kernel<<<512, 256, 0, stream>>>(
            o_part, ssum_part, pw + (size_t)i * D * D, pb + i * D,
            A_ln1, n2g + i * D, n2b + i * D,
            f1w + (size_t)i * D * 2 * D, f1b + i * 2 * D,
            f2w + (size_t)i * 2 * D * D, f2b + i * D,
            A_h);
    }

    // pack h -> bf16 halo'd channel-last, then MFMA GEMM conv_up (+pixel shuffle, bf16 U)
    pack_h_kernel<<<1634, 256, 0, stream>>>(A_h, hbfp);
    conv_up_mfma_kernel<<<6144, 256, 0, stream>>>(hbfp, Wp, upb, U_bf);

    // last conv: MFMA im2col GEMM over channel-last bf16 U -> f32 out
    lastconv_mfma_kernel<<<2048, 256, 0, stream>>>(
        U_bf, Wp2, hbfp + 2 * 66 * 66 * 48, lb, (float*)d_out);
}

// Round 6
// 293.082 us; speedup vs baseline: 1.3613x; 1.0577x over previous
//
#include <hip/hip_runtime.h>
#include <hip/hip_bf16.h>
#include <math.h>

#define BB 2
#define D 48
#define HH 64
#define WW 64
#define LL 4096      // HH*WW
#define NHEADS 4
#define HD 12
#define NBLK 4
#define CUP 768
#define H2 256
#define W2 256

#define NSPLIT 4
#define OPART_STRIDE 393216   // B*L*48 floats per split

typedef __attribute__((ext_vector_type(8))) short short8v;
typedef __attribute__((ext_vector_type(4))) float f32x4;
typedef unsigned long long u64;

__device__ __forceinline__ short f2bf(float f) {
    __hip_bfloat16 h = __float2bfloat16(f);
    union { __hip_bfloat16 b; short s; } u; u.b = h; return u.s;
}
__device__ __forceinline__ float bf2f(short s) {
    union { float f; unsigned u; } x;
    x.u = ((unsigned)(unsigned short)s) << 16;
    return x.f;
}
// raw 2^x (hardware approx, ~1 ulp; inputs are tiny softmax scores -> safe)
__device__ __forceinline__ float exp2_raw(float x) {
    float r; asm("v_exp_f32 %0, %1" : "=v"(r) : "v"(x)); return r;
}

// ---------------- generic 3x3 SAME conv, f32 (used for conv_first only) ----------------
__global__ void conv3x3_kernel(const float* __restrict__ in, const float* __restrict__ w,
                               const float* __restrict__ bias, float* __restrict__ out,
                               int Cin, int Cout) {
    int idx = blockIdx.x * blockDim.x + threadIdx.x;
    int total = BB * Cout * HH * WW;
    if (idx >= total) return;
    int x = idx % WW;
    int y = (idx / WW) % HH;
    int co = (idx / (WW * HH)) % Cout;
    int b = idx / (WW * HH * Cout);
    float s = bias[co];
    for (int ci = 0; ci < Cin; ci++) {
        const float* ip = in + ((size_t)(b * Cin + ci) * HH) * WW;
        const float* wp = w + (size_t)(co * Cin + ci) * 9;
        #pragma unroll
        for (int ky = 0; ky < 3; ky++) {
            int iy = y + ky - 1;
            if (iy < 0 || iy >= HH) continue;
            #pragma unroll
            for (int kx = 0; kx < 3; kx++) {
                int ix = x + kx - 1;
                if (ix < 0 || ix >= WW) continue;
                s += ip[iy * WW + ix] * wp[ky * 3 + kx];
            }
        }
    }
    out[idx] = s;
}

// ---- pack h (NCHW f32) -> bf16 channel-last with 1-px zero halo: [b][66][66][48] + 64 zero ----
__global__ __launch_bounds__(256) void pack_h_kernel(const float* __restrict__ h,
                                                     short* __restrict__ hbfp) {
    int idx = blockIdx.x * 256 + threadIdx.x;
    const int TOT = 2 * 66 * 66 * 48;    // 418176
    if (idx >= TOT + 64) return;
    if (idx >= TOT) { hbfp[idx] = 0; return; }
    int ci = idx % 48;
    int p = idx / 48;
    int xx = p % 66;
    int q = p / 66;
    int yy = q % 66;
    int b = q / 66;
    short v = 0;
    if (yy >= 1 && yy <= 64 && xx >= 1 && xx <= 64)
        v = f2bf(h[((size_t)(b * 48 + ci) << 12) + (yy - 1) * 64 + (xx - 1)]);
    hbfp[idx] = v;
}

// ---- pack conv_up weights into B-fragment order: Wp[n16][s][col][g][j], K=tap*48+ci pad 448 ----
__global__ __launch_bounds__(256) void pack_w_kernel(const float* __restrict__ w,
                                                     short* __restrict__ Wp) {
    int idx = blockIdx.x * 256 + threadIdx.x;
    if (idx >= 48 * 14 * 512) return;    // 344064
    int j = idx & 7;
    int g = (idx >> 3) & 3;
    int col = (idx >> 5) & 15;
    int s = (idx >> 9) % 14;
    int n16 = idx / (14 * 512);
    int k = 32 * s + 8 * g + j;
    short v = 0;
    if (k < 432) {
        int tap = k / 48, ci = k - tap * 48;
        int co = n16 * 16 + col;
        v = f2bf(w[((size_t)co * 48 + ci) * 9 + tap]);
    }
    Wp[idx] = v;
}

// ---- pack last-conv weights into B-fragment order: Wp2[s][col][g][j], cols 3..15 zero ----
__global__ __launch_bounds__(256) void pack_lw_kernel(const float* __restrict__ w,
                                                      short* __restrict__ Wp2) {
    int idx = blockIdx.x * 256 + threadIdx.x;
    if (idx >= 14 * 512) return;         // 7168
    int j = idx & 7;
    int g = (idx >> 3) & 3;
    int col = (idx >> 5) & 15;
    int s = idx >> 9;
    int k = 32 * s + 8 * g + j;
    short v = 0;
    if (k < 432 && col < 3) {
        int tap = k / 48, ci = k - tap * 48;
        v = f2bf(w[((size_t)col * 48 + ci) * 9 + tap]);
    }
    Wp2[idx] = v;
}

// ---- conv_up as bf16 MFMA GEMM, reuse-restructured: each wave owns one 16-px strip
//      (A held in 14 registers, loaded ONCE), loops all 48 n16 tiles with B frags
//      double-buffered from L2 (block's 2 waves share B via L1). Output staged in
//      wave-private LDS [4 rows][64 x][48 ch] then stored as contiguous vec8 runs:
//      kills the 4x write amplification of the scattered pixel-shuffle stores.
//      U is CHANNEL-LAST: [b][256][256][48] bf16. No __syncthreads anywhere. ----
#define CU_LOADB(P, n) { \
    _Pragma("unroll") \
    for (int s_ = 0; s_ < 14; s_++) \
        P[s_] = *(const short8v*)(Wb + (size_t)(n) * 7168 + s_ * 512); }

#define CU_COMP(P, n) { \
    f32x4 acc = {0.f, 0.f, 0.f, 0.f}; \
    _Pragma("unroll") \
    for (int s_ = 0; s_ < 14; s_++) \
        acc = __builtin_amdgcn_mfma_f32_16x16x32_bf16(av[s_], P[s_], acc, 0, 0, 0); \
    float bval = bias[(n) * 16 + col]; \
    _Pragma("unroll") \
    for (int j = 0; j < 4; j++) \
        Sw[sbase + j * 192 + (n)] = f2bf(acc[j] + bval); }

__global__ __launch_bounds__(128) void conv_up_mfma_kernel(const short* __restrict__ hbfp,
                                                           const short* __restrict__ Wp,
                                                           const float* __restrict__ bias,
                                                           short* __restrict__ U) {
    __shared__ short Sb[2][12288];       // 48 KB: per-wave out-staging (wave-private)
    int tid = threadIdx.x;
    int wave = tid >> 6, lane = tid & 63;
    int mt = blockIdx.x * 2 + wave;      // 512 strips: b(2) | y(64) | xt(4)
    int b = mt >> 8;
    int rem = mt & 255;
    int y = rem >> 2;
    int xt = rem & 3;
    int col = lane & 15;
    int g = lane >> 4;
    int x = xt * 16 + col;               // A-row pixel x

    const short* zb = hbfp + 2 * 66 * 66 * 48;   // 64 zero shorts

    // A fragments in registers, loaded once (same im2col addressing as before)
    short8v av[14];
    #pragma unroll
    for (int s = 0; s < 14; s++) {
        int gg = 4 * s + g;
        int tap = (gg * 171) >> 10;      // gg/6 for gg<60
        int cig = gg - tap * 6;
        int dy = (tap * 11) >> 5;        // tap/3 for tap<9(+)
        int dx = tap - dy * 3;
        const short* ap = hbfp + ((size_t)((b * 66 + y + dy) * 66 + (x + dx)) * 48 + cig * 8);
        ap = (gg < 54) ? ap : zb;
        av[s] = *(const short8v*)ap;
    }

    const short* Wb = Wp + col * 32 + g * 8;
    short* Sw = Sb[wave];
    int dyq = col >> 2, dxq = col & 3;
    int sbase = dyq * 3072 + (16 * g + dxq) * 48;   // + j*4*48 + n16

    short8v Ba[14], Bb[14];
    CU_LOADB(Ba, 0);
    for (int n = 0; n < 48; n += 2) {
        CU_LOADB(Bb, n + 1);
        CU_COMP(Ba, n);
        if (n + 2 < 48) CU_LOADB(Ba, n + 2);
        CU_COMP(Bb, n + 1);
    }

    // coalesced store: 4 rows x 3072 shorts contiguous each
    short* Ub = U + (((size_t)(b * 256 + 4 * y) * 256) + xt * 64) * 48;
    for (int i = lane; i < 1536; i += 64) {
        int row = i / 384;
        int w8 = i - row * 384;
        short8v v = *(const short8v*)(Sw + (size_t)i * 8);
        *(short8v*)(Ub + (size_t)row * 256 * 48 + w8 * 8) = v;
    }
}

// ---- zero bf16 pad regions; plant bf16 1.0 in Vr's padded row dd==12 (sum-row trick) ----
__global__ void zero16_kernel(u64* __restrict__ p, int n) {
    int i = blockIdx.x * 256 + threadIdx.x;
    if (i >= n) return;
    u64 fill = 0ull;
    // short offset of this 8-short chunk, relative to Vr start (Q:1M + K:1M shorts before it)
    int rel = 8 * i - 2097152;
    if (rel >= 0 && rel < 524288 && (((rel >> 5) & 15) == 12))
        fill = 0x3F803F803F803F80ull;     // bf16 1.0 x4
    p[2 * i] = fill;
    p[2 * i + 1] = fill;
}

// ---- fused: LN1 (NCHW) -> ln1 rows + qkv matmul -> bf16 Q/K/Vr (16-tok tiles) ----
__global__ __launch_bounds__(256) void fused_ln1_qkv_kernel(
    const float* __restrict__ hsrc, const float* __restrict__ g1, const float* __restrict__ b1,
    const float* __restrict__ w, const float* __restrict__ bias,
    float* __restrict__ ln1, short* __restrict__ Qbf, short* __restrict__ Kbf,
    short* __restrict__ Vr) {
    __shared__ float hs[48 * 17];
    __shared__ float lnr[16 * 49];
    __shared__ float wl[48 * 144];
    int blk = blockIdx.x;
    int b = blk >> 8;
    int pos0 = (blk & 255) * 16;
    int tid = threadIdx.x;

    for (int i = tid; i < 48 * 144; i += 256) wl[i] = w[i];
    for (int i = tid; i < 48 * 16; i += 256) {
        int ch = i >> 4, p = i & 15;
        hs[ch * 17 + p] = hsrc[((size_t)b * 48 + ch) * 4096 + pos0 + p];
    }
    __syncthreads();

    int tok = tid >> 4, oct = tid & 15;
    int pos = pos0 + tok;
    float v[3];
    float s = 0.f, s2 = 0.f;
    #pragma unroll
    for (int j = 0; j < 3; j++) {
        float x = hs[(oct * 3 + j) * 17 + tok];
        v[j] = x; s += x; s2 += x * x;
    }
    #pragma unroll
    for (int msk = 1; msk < 16; msk <<= 1) {
        s += __shfl_xor(s, msk, 64);
        s2 += __shfl_xor(s2, msk, 64);
    }
    float mu = s * (1.f / 48.f);
    float var = s2 * (1.f / 48.f) - mu * mu;
    float rs = rsqrtf(var + 1e-5f);
    float* go = ln1 + ((size_t)b * 4096 + pos) * 48 + oct * 3;
    #pragma unroll
    for (int j = 0; j < 3; j++) {
        int c = oct * 3 + j;
        float y = (v[j] - mu) * rs * g1[c] + b1[c];
        lnr[tok * 49 + c] = y;
        go[j] = y;
    }
    __syncthreads();

    int c0 = oct * 9;
    float acc[9];
    #pragma unroll
    for (int j = 0; j < 9; j++) acc[j] = bias[c0 + j];
    #pragma unroll 4
    for (int k = 0; k < 48; k++) {
        float a = lnr[tok * 49 + k];
        const float* wr = wl + k * 144 + c0;
        #pragma unroll
        for (int j = 0; j < 9; j++) acc[j] += a * wr[j];
    }

    // 1/sqrt(12) * log2(e): softmax exp becomes a single raw v_exp_f32 (2^x)
    const float scale = 0.41647023f;
    int sstep = pos >> 5, r = pos & 31;
    int g2 = (r < 16) ? (r >> 2) : ((r - 16) >> 2);
    int j2 = (r < 16) ? (r & 3) : 4 + ((r - 16) & 3);
    #pragma unroll
    for (int j = 0; j < 9; j++) {
        int c = c0 + j;
        int which = (c >= 96) ? 2 : (c >= 48 ? 1 : 0);
        int rem = c - which * 48;
        int hh = rem / 12;
        int dd = rem - hh * 12;
        int bh = b * 4 + hh;
        if (which == 0)
            Qbf[((size_t)bh * 4096 + pos) * 32 + dd] = f2bf(acc[j] * scale);
        else if (which == 1)
            Kbf[((size_t)bh * 4096 + pos) * 32 + dd] = f2bf(acc[j]);
        else
            Vr[((size_t)bh * 128 + sstep) * 512 + dd * 32 + g2 * 8 + j2] = f2bf(acc[j]);
    }
}

// ---- fused: split-combine + proj + resid + LN2 + fc1 + GELU + fc2 + resid + h-accum ----
__global__ __launch_bounds__(256) void fused_mlp_kernel(
    const float* __restrict__ opart, const float* __restrict__ ssump,
    const float* __restrict__ pwg, const float* __restrict__ pb,
    const float* __restrict__ ln1, const float* __restrict__ g2v, const float* __restrict__ b2v,
    const float* __restrict__ f1w, const float* __restrict__ f1b,
    const float* __restrict__ f2w, const float* __restrict__ f2b,
    float* __restrict__ hbuf) {
    __shared__ float sm[14640];
    float* wp  = sm;            // 2304  (48x48 proj)
    float* w1  = sm + 2304;     // 4608  (48x96 fc1)
    float* w2  = sm + 6912;     // 4608  (96x48 fc2)
    float* arf = sm + 11520;    // 784   (16x49) attn rows, reused as fc2-out
    float* lnr = sm + 12304;    // 784   (16x49) ln2 rows
    float* m1v = sm + 13088;    // 1552  (16x97) gelu(fc1)

    int blk = blockIdx.x;
    int b = blk >> 8;
    int pos0 = (blk & 255) * 16;
    int tid = threadIdx.x;

    for (int i = tid; i < 2304; i += 256) wp[i] = pwg[i];
    for (int i = tid; i < 4608; i += 256) w1[i] = f1w[i];
    for (int i = tid; i < 4608; i += 256) w2[i] = f2w[i];
    // combine split partials -> normalized attention rows (per-thread, no extra sync deps)
    for (int i = tid; i < 768; i += 256) {
        int t = i / 48, c = i - (i / 48) * 48;
        int hh = c / 12;
        size_t base = ((size_t)b * 4096 + pos0) * 48 + i;
        float stot = 0.f, s = 0.f;
        #pragma unroll
        for (int sp = 0; sp < NSPLIT; sp++) {
            stot += ssump[((size_t)sp * 8 + b * 4 + hh) * 4096 + pos0 + t];
            s += opart[base + (size_t)sp * OPART_STRIDE];
        }
        arf[t * 49 + c] = s / stot;
    }
    __syncthreads();

    int tok = tid >> 4, oct = tid & 15;
    size_t gtok = (size_t)b * 4096 + pos0 + tok;
    int c0 = oct * 3;
    float acc[3];
    #pragma unroll
    for (int j = 0; j < 3; j++) acc[j] = pb[c0 + j];
    #pragma unroll 4
    for (int k = 0; k < 48; k++) {
        float a = arf[tok * 49 + k];
        const float* wr = wp + k * 48 + c0;
        #pragma unroll
        for (int j = 0; j < 3; j++) acc[j] += a * wr[j];
    }
    const float* rp = ln1 + gtok * 48 + c0;
    float x[3]; float s = 0.f, s2 = 0.f;
    #pragma unroll
    for (int j = 0; j < 3; j++) {
        float t = acc[j] + rp[j];
        x[j] = t; s += t; s2 += t * t;
    }
    #pragma unroll
    for (int msk = 1; msk < 16; msk <<= 1) {
        s += __shfl_xor(s, msk, 64);
        s2 += __shfl_xor(s2, msk, 64);
    }
    float mu = s * (1.f / 48.f), var = s2 * (1.f / 48.f) - mu * mu;
    float rs = rsqrtf(var + 1e-5f);
    #pragma unroll
    for (int j = 0; j < 3; j++) {
        int c = c0 + j;
        lnr[tok * 49 + c] = (x[j] - mu) * rs * g2v[c] + b2v[c];
    }
    __syncthreads();

    // fc1 + GELU -> m1v (LDS only)
    int d0 = oct * 6;
    float a2[6];
    #pragma unroll
    for (int j = 0; j < 6; j++) a2[j] = f1b[d0 + j];
    #pragma unroll 4
    for (int k = 0; k < 48; k++) {
        float a = lnr[tok * 49 + k];
        const float* wr = w1 + k * 96 + d0;
        #pragma unroll
        for (int j = 0; j < 6; j++) a2[j] += a * wr[j];
    }
    #pragma unroll
    for (int j = 0; j < 6; j++) {
        float g = a2[j];
        m1v[tok * 97 + d0 + j] = 0.5f * g * (1.f + erff(g * 0.70710678118654752f));
    }
    __syncthreads();

    // fc2 + ln2-residual -> arf (reused)
    float f2acc[3];
    #pragma unroll
    for (int j = 0; j < 3; j++) f2acc[j] = f2b[c0 + j];
    #pragma unroll 4
    for (int k = 0; k < 96; k++) {
        float a = m1v[tok * 97 + k];
        const float* wr = w2 + k * 48 + c0;
        #pragma unroll
        for (int j = 0; j < 3; j++) f2acc[j] += a * wr[j];
    }
    __syncthreads();
    #pragma unroll
    for (int j = 0; j < 3; j++)
        arf[tok * 49 + c0 + j] = f2acc[j] + lnr[tok * 49 + c0 + j];
    __syncthreads();

    // cooperative coalesced transposed accumulate into h (NCHW)
    for (int i = tid; i < 768; i += 256) {
        int c = i >> 4, t = i & 15;
        hbuf[(((size_t)(b * 48 + c)) << 12) + pos0 + t] += arf[t * 49 + c];
    }
}

// ---- MFMA flash attention: 32 q/wave (2 fragments sharing K/V loads), split-K x4,
//      128-key chunk double-buffer (R1-proven pipeline). No-max softmax: partials
//      (o, sum p) are plain sums -> additive combine in fused_mlp. Row sum via V
//      ones-row (dd==12). 2 frags halve per-dispatch L2 traffic (786 -> 393 MB).
#define LOADCH(P, c) { \
    _Pragma("unroll") \
    for (int s_ = 0; s_ < 4; s_++) { \
        const short* kp_ = Kb + ((size_t)((c) * 128 + s_ * 32 + col)) * 32 + g * 8; \
        P##k0[s_] = *(const short8v*)(kp_); \
        P##k1[s_] = *(const short8v*)(kp_ + 512); \
        P##v[s_]  = *(const short8v*)(Vrb + ((c) * 4 + s_) * 512 + vbase); \
    } }

#define STEP2(kc0, kc1, vv) { \
    f32x4 z_ = {0.f, 0.f, 0.f, 0.f}; \
    f32x4 sa1 = __builtin_amdgcn_mfma_f32_16x16x32_bf16(kc0, qb0, z_, 0, 0, 0); \
    f32x4 sa2 = __builtin_amdgcn_mfma_f32_16x16x32_bf16(kc1, qb0, z_, 0, 0, 0); \
    f32x4 sb1 = __builtin_amdgcn_mfma_f32_16x16x32_bf16(kc0, qb1, z_, 0, 0, 0); \
    f32x4 sb2 = __builtin_amdgcn_mfma_f32_16x16x32_bf16(kc1, qb1, z_, 0, 0, 0); \
    float a0 = exp2_raw(sa1[0]), a1 = exp2_raw(sa1[1]); \
    float a2 = exp2_raw(sa1[2]), a3 = exp2_raw(sa1[3]); \
    float a4 = exp2_raw(sa2[0]), a5 = exp2_raw(sa2[1]); \
    float a6 = exp2_raw(sa2[2]), a7 = exp2_raw(sa2[3]); \
    float e0 = exp2_raw(sb1[0]), e1 = exp2_raw(sb1[1]); \
    float e2 = exp2_raw(sb1[2]), e3 = exp2_raw(sb1[3]); \
    float e4 = exp2_raw(sb2[0]), e5 = exp2_raw(sb2[1]); \
    float e6 = exp2_raw(sb2[2]), e7 = exp2_raw(sb2[3]); \
    union { short8v sv; unsigned u[4]; } pa_, pe_; \
    asm("v_cvt_pk_bf16_f32 %0, %1, %2" : "=v"(pa_.u[0]) : "v"(a0), "v"(a1)); \
    asm("v_cvt_pk_bf16_f32 %0, %1, %2" : "=v"(pa_.u[1]) : "v"(a2), "v"(a3)); \
    asm("v_cvt_pk_bf16_f32 %0, %1, %2" : "=v"(pa_.u[2]) : "v"(a4), "v"(a5)); \
    asm("v_cvt_pk_bf16_f32 %0, %1, %2" : "=v"(pa_.u[3]) : "v"(a6), "v"(a7)); \
    asm("v_cvt_pk_bf16_f32 %0, %1, %2" : "=v"(pe_.u[0]) : "v"(e0), "v"(e1)); \
    asm("v_cvt_pk_bf16_f32 %0, %1, %2" : "=v"(pe_.u[1]) : "v"(e2), "v"(e3)); \
    asm("v_cvt_pk_bf16_f32 %0, %1, %2" : "=v"(pe_.u[2]) : "v"(e4), "v"(e5)); \
    asm("v_cvt_pk_bf16_f32 %0, %1, %2" : "=v"(pe_.u[3]) : "v"(e6), "v"(e7)); \
    o0 = __builtin_amdgcn_mfma_f32_16x16x32_bf16(vv, pa_.sv, o0, 0, 0, 0); \
    o1 = __builtin_amdgcn_mfma_f32_16x16x32_bf16(vv, pe_.sv, o1, 0, 0, 0); }

#define COMPUTECH2(P) { \
    STEP2(P##k0[0], P##k1[0], P##v[0]); \
    STEP2(P##k0[1], P##k1[1], P##v[1]); \
    STEP2(P##k0[2], P##k1[2], P##v[2]); \
    STEP2(P##k0[3], P##k1[3], P##v[3]); }

__global__ __launch_bounds__(256) void attn_mfma_kernel(const short* __restrict__ Qbf,
                                                        const short* __restrict__ Kbf,
                                                        const short* __restrict__ Vr,
                                                        float* __restrict__ opart,
                                                        float* __restrict__ ssump) {
    int bid = blockIdx.x;                 // split(4) | qblk(32) | bh(8) = 1024 blocks
    int bh = bid & 7;
    int qblk = (bid >> 3) & 31;
    int split = bid >> 8;
    int h = bh & 3, b = bh >> 2;
    int tid = threadIdx.x;
    int wave = tid >> 6;
    int lane = tid & 63;
    int q0 = qblk * 128 + wave * 32;      // 32 q per wave (2 x 16-q fragments)
    int col = lane & 15;
    int g = lane >> 4;

    const short* Kb  = Kbf + (size_t)bh * LL * 32 + (size_t)split * 1024 * 32;
    const short* Vrb = Vr + (size_t)bh * 65536 + (size_t)split * 32 * 512;
    int vbase = col * 32 + g * 8;

    short8v qb0 = *(const short8v*)(Qbf + ((size_t)bh * LL + q0 + col) * 32 + g * 8);
    short8v qb1 = *(const short8v*)(Qbf + ((size_t)bh * LL + q0 + 16 + col) * 32 + g * 8);

    f32x4 o0 = {0.f, 0.f, 0.f, 0.f};
    f32x4 o1 = {0.f, 0.f, 0.f, 0.f};

    short8v a_k0[4], a_k1[4], a_v[4];
    short8v b_k0[4], b_k1[4], b_v[4];

    LOADCH(a_, 0);
    for (int c = 0; c < 8; c += 2) {
        LOADCH(b_, c + 1);
        COMPUTECH2(a_);
        if (c + 2 < 8) LOADCH(a_, c + 2);
        COMPUTECH2(b_);
    }

    // row 12 of o (lane group g==3, j==0) holds this split's sum(p) via V's ones-row
    float ssa = __shfl(o0[0], 48 + col, 64);
    float ssb = __shfl(o1[0], 48 + col, 64);

    float* op = opart + (size_t)split * OPART_STRIDE
              + ((size_t)b * 4096 + q0 + col) * 48 + h * HD;
    #pragma unroll
    for (int j = 0; j < 4; j++) {
        int d = 4 * g + j;
        if (d < HD) {
            op[d] = o0[j];
            op[16 * 48 + d] = o1[j];
        }
    }
    if (lane < 16) {
        float* sp = ssump + ((size_t)split * 8 + bh) * 4096 + q0 + col;
        sp[0] = ssa;
        sp[16] = ssb;
    }
}

// ---- last conv as bf16 MFMA GEMM over channel-last U: M=131072 px, N=16 (3 real oc),
//      K=448 (tap*48+ci). Per-wave 16-px tile, 14 MFMAs, no LDS, no syncs. Boundary
//      taps resolved by zero-block pointer select (same idiom as conv_up's gg<54). ----
__global__ __launch_bounds__(256) void lastconv_mfma_kernel(const short* __restrict__ U,
                                                            const short* __restrict__ Wp2,
                                                            const short* __restrict__ zb,
                                                            const float* __restrict__ bias,
                                                            float* __restrict__ out) {
    int tid = threadIdx.x;
    int wave = tid >> 6, lane = tid & 63;
    int t = blockIdx.x * 4 + wave;        // 8192 tiles: b(2) | y(256) | xt(16)
    int xt = t & 15;
    int yy = (t >> 4) & 255;
    int b = t >> 12;
    int col = lane & 15, g = lane >> 4;
    int x = xt * 16 + col;                // A-row pixel x

    const short* Ub = U + (size_t)b * 65536 * 48;
    const short* Bp = Wp2 + col * 32 + g * 8;

    f32x4 acc = {0.f, 0.f, 0.f, 0.f};
    #pragma unroll
    for (int s = 0; s < 14; s++) {
        int gg = 4 * s + g;
        int tap = (gg * 171) >> 10;       // gg/6 for gg<60
        int cig = gg - tap * 6;
        int dy3 = (tap * 11) >> 5;        // tap/3 for tap<9(+)
        int dy = dy3 - 1;
        int dx = tap - dy3 * 3 - 1;
        int yq = yy + dy, xq = x + dx;
        bool ok = (gg < 54) && (yq >= 0) && (yq < 256) && (xq >= 0) && (xq < 256);
        const short* ap = Ub + (ptrdiff_t)(yq * 256 + xq) * 48 + cig * 8;
        ap = ok ? ap : zb;
        short8v av = *(const short8v*)ap;
        short8v bv = *(const short8v*)(Bp + s * 512);
        acc = __builtin_amdgcn_mfma_f32_16x16x32_bf16(av, bv, acc, 0, 0, 0);
    }

    if (col < 3) {
        float bval = bias[col];
        float* op = out + ((size_t)(b * 3 + col) * 256 + yy) * 256 + xt * 16 + 4 * g;
        #pragma unroll
        for (int j = 0; j < 4; j++)
            op[j] = acc[j] + bval;        // C row r=4g+j = pixel-x offset (m89 mapping)
    }
}

static inline int gs(int n) { return (n + 255) / 256; }

extern "C" void kernel_launch(void* const* d_in, const int* in_sizes, int n_in,
                              void* d_out, int out_size, void* d_ws, size_t ws_size,
                              hipStream_t stream) {
    const float* x    = (const float*)d_in[0];
    const float* cf_w = (const float*)d_in[1];
    const float* cf_b = (const float*)d_in[2];
    const float* n1g  = (const float*)d_in[3];
    const float* n1b  = (const float*)d_in[4];
    const float* qkvw = (const float*)d_in[5];
    const float* qkvb = (const float*)d_in[6];
    const float* pw   = (const float*)d_in[7];
    const float* pb   = (const float*)d_in[8];
    const float* n2g  = (const float*)d_in[9];
    const float* n2b  = (const float*)d_in[10];
    const float* f1w  = (const float*)d_in[11];
    const float* f1b  = (const float*)d_in[12];
    const float* f2w  = (const float*)d_in[13];
    const float* f2b  = (const float*)d_in[14];
    const float* upw  = (const float*)d_in[15];
    const float* upb  = (const float*)d_in[16];
    const float* lw   = (const float*)d_in[17];
    const float* lb   = (const float*)d_in[18];

    float* ws = (float*)d_ws;
    const int S_h = BB * D * LL;            // 393216
    float* A_h   = ws;
    float* pool  = ws + S_h;
    float* A_ln1 = pool;

    // U channel-last bf16: [b][256][256][48] shorts = 6291456 shorts = 3145728 floats at pool[0]
    // (written after the block loop; aliases A_ln1 + o_part, both dead by then)
    short* U_bf = (short*)pool;
    // attention split partials: o_part [4][B*L*48]
    float* o_part = pool + 1572864;                    // ends 3145728
    short* Qbf  = (short*)(pool + 3538944);
    short* Kbf  = Qbf + BB * NHEADS * LL * 32;         // +1048576 shorts
    short* Vr   = Kbf + BB * NHEADS * LL * 32;         // ends pool+4849664 floats
    // packs live in the dead gap after Vr (proven R3/R4 footprint, no growth)
    short* hbfp = (short*)(pool + 4849664);            // 418240 shorts -> ends 5058784
    short* Wp   = (short*)(pool + 5058784);            // 344064 shorts -> ends 5230816
    short* Wp2  = (short*)(pool + 5230816);            // 7168 shorts   -> ends 5234400
    // ssum partials
    float* ssum_part = pool + 5898240;                 // 131072 floats -> ends 6029312

    // conv_first (3 -> 48)
    conv3x3_kernel<<<gs(S_h), 256, 0, stream>>>(x, cf_w, cf_b, A_h, 3, D);

    // zero Q/K/Vr (pads must be 0; Vr ones-row planted; real entries overwritten every block)
    zero16_kernel<<<1536, 256, 0, stream>>>((u64*)Qbf, 393216);
    // pack conv_up + last-conv weights (input-only dependencies)
    pack_w_kernel<<<1344, 256, 0, stream>>>(upw, Wp);
    pack_lw_kernel<<<28, 256, 0, stream>>>(lw, Wp2);

    for (int i = 0; i < NBLK; i++) {
        fused_ln1_qkv_kernel<<<512, 256, 0, stream>>>(
            A_h, n1g + i * D, n1b + i * D,
            qkvw + (size_t)i * D * 3 * D, qkvb + i * 3 * D,
            A_ln1, Qbf, Kbf, Vr);
        attn_mfma_kernel<<<8 * 32 * NSPLIT, 256, 0, stream>>>(Qbf, Kbf, Vr, o_part, ssum_part);
        fused_mlp_kernel<<<512, 256, 0, stream>>>(
            o_part, ssum_part, pw + (size_t)i * D * D, pb + i * D,
            A_ln1, n2g + i * D, n2b + i * D,
            f1w + (size_t)i * D * 2 * D, f1b + i * 2 * D,
            f2w + (size_t)i * 2 * D * D, f2b + i * D,
            A_h);
    }

    // pack h -> bf16 halo'd channel-last, then reuse-restructured MFMA conv_up -> bf16 U
    pack_h_kernel<<<1634, 256, 0, stream>>>(A_h, hbfp);
    conv_up_mfma_kernel<<<256, 128, 0, stream>>>(hbfp, Wp, upb, U_bf);

    // last conv: MFMA im2col GEMM over channel-last bf16 U -> f32 out
    lastconv_mfma_kernel<<<2048, 256, 0, stream>>>(
        U_bf, Wp2, hbfp + 2 * 66 * 66 * 48, lb, (float*)d_out);
}

// Round 7
// 278.944 us; speedup vs baseline: 1.4303x; 1.0507x over previous
//
#include <hip/hip_runtime.h>
#include <hip/hip_bf16.h>
#include <math.h>

#define BB 2
#define D 48
#define HH 64
#define WW 64
#define LL 4096      // HH*WW
#define NHEADS 4
#define HD 12
#define NBLK 4
#define CUP 768
#define H2 256
#define W2 256

#define NSPLIT 4
#define OPART_STRIDE 393216   // B*L*48 floats per split

typedef __attribute__((ext_vector_type(8))) short short8v;
typedef __attribute__((ext_vector_type(4))) float f32x4;
typedef unsigned long long u64;

__device__ __forceinline__ short f2bf(float f) {
    __hip_bfloat16 h = __float2bfloat16(f);
    union { __hip_bfloat16 b; short s; } u; u.b = h; return u.s;
}
__device__ __forceinline__ float bf2f(short s) {
    union { float f; unsigned u; } x;
    x.u = ((unsigned)(unsigned short)s) << 16;
    return x.f;
}
// raw 2^x (hardware approx, ~1 ulp; inputs are tiny softmax scores -> safe)
__device__ __forceinline__ float exp2_raw(float x) {
    float r; asm("v_exp_f32 %0, %1" : "=v"(r) : "v"(x)); return r;
}

// ---------------- generic 3x3 SAME conv, f32 (used for conv_first only) ----------------
__global__ void conv3x3_kernel(const float* __restrict__ in, const float* __restrict__ w,
                               const float* __restrict__ bias, float* __restrict__ out,
                               int Cin, int Cout) {
    int idx = blockIdx.x * blockDim.x + threadIdx.x;
    int total = BB * Cout * HH * WW;
    if (idx >= total) return;
    int x = idx % WW;
    int y = (idx / WW) % HH;
    int co = (idx / (WW * HH)) % Cout;
    int b = idx / (WW * HH * Cout);
    float s = bias[co];
    for (int ci = 0; ci < Cin; ci++) {
        const float* ip = in + ((size_t)(b * Cin + ci) * HH) * WW;
        const float* wp = w + (size_t)(co * Cin + ci) * 9;
        #pragma unroll
        for (int ky = 0; ky < 3; ky++) {
            int iy = y + ky - 1;
            if (iy < 0 || iy >= HH) continue;
            #pragma unroll
            for (int kx = 0; kx < 3; kx++) {
                int ix = x + kx - 1;
                if (ix < 0 || ix >= WW) continue;
                s += ip[iy * WW + ix] * wp[ky * 3 + kx];
            }
        }
    }
    out[idx] = s;
}

// ---- pack h (NCHW f32) -> bf16 channel-last with 1-px zero halo: [b][66][66][48] + 64 zero ----
__global__ __launch_bounds__(256) void pack_h_kernel(const float* __restrict__ h,
                                                     short* __restrict__ hbfp) {
    int idx = blockIdx.x * 256 + threadIdx.x;
    const int TOT = 2 * 66 * 66 * 48;    // 418176
    if (idx >= TOT + 64) return;
    if (idx >= TOT) { hbfp[idx] = 0; return; }
    int ci = idx % 48;
    int p = idx / 48;
    int xx = p % 66;
    int q = p / 66;
    int yy = q % 66;
    int b = q / 66;
    short v = 0;
    if (yy >= 1 && yy <= 64 && xx >= 1 && xx <= 64)
        v = f2bf(h[((size_t)(b * 48 + ci) << 12) + (yy - 1) * 64 + (xx - 1)]);
    hbfp[idx] = v;
}

// ---- pack conv_up weights into B-fragment order: Wp[n16][s][col][g][j], K=tap*48+ci pad 448 ----
__global__ __launch_bounds__(256) void pack_w_kernel(const float* __restrict__ w,
                                                     short* __restrict__ Wp) {
    int idx = blockIdx.x * 256 + threadIdx.x;
    if (idx >= 48 * 14 * 512) return;    // 344064
    int j = idx & 7;
    int g = (idx >> 3) & 3;
    int col = (idx >> 5) & 15;
    int s = (idx >> 9) % 14;
    int n16 = idx / (14 * 512);
    int k = 32 * s + 8 * g + j;
    short v = 0;
    if (k < 432) {
        int tap = k / 48, ci = k - tap * 48;
        int co = n16 * 16 + col;
        v = f2bf(w[((size_t)co * 48 + ci) * 9 + tap]);
    }
    Wp[idx] = v;
}

// ---- pack last-conv weights into B-fragment order: Wp2[s][col][g][j], cols 3..15 zero ----
__global__ __launch_bounds__(256) void pack_lw_kernel(const float* __restrict__ w,
                                                      short* __restrict__ Wp2) {
    int idx = blockIdx.x * 256 + threadIdx.x;
    if (idx >= 14 * 512) return;         // 7168
    int j = idx & 7;
    int g = (idx >> 3) & 3;
    int col = (idx >> 5) & 15;
    int s = idx >> 9;
    int k = 32 * s + 8 * g + j;
    short v = 0;
    if (k < 432 && col < 3) {
        int tap = k / 48, ci = k - tap * 48;
        v = f2bf(w[((size_t)col * 48 + ci) * 9 + tap]);
    }
    Wp2[idx] = v;
}

// ---- conv_up as bf16 MFMA GEMM, reuse-restructured: each wave owns one 16-px strip
//      (A held in 14 registers, loaded ONCE), loops all 48 n16 tiles with B frags
//      double-buffered from L2 (block's 2 waves share B via L1). Output staged in
//      wave-private LDS [4 rows][64 x][48 ch] then stored as contiguous vec8 runs:
//      kills the 4x write amplification of the scattered pixel-shuffle stores.
//      U is CHANNEL-LAST: [b][256][256][48] bf16. No __syncthreads anywhere. ----
#define CU_LOADB(P, n) { \
    _Pragma("unroll") \
    for (int s_ = 0; s_ < 14; s_++) \
        P[s_] = *(const short8v*)(Wb + (size_t)(n) * 7168 + s_ * 512); }

#define CU_COMP(P, n) { \
    f32x4 acc = {0.f, 0.f, 0.f, 0.f}; \
    _Pragma("unroll") \
    for (int s_ = 0; s_ < 14; s_++) \
        acc = __builtin_amdgcn_mfma_f32_16x16x32_bf16(av[s_], P[s_], acc, 0, 0, 0); \
    float bval = bias[(n) * 16 + col]; \
    _Pragma("unroll") \
    for (int j = 0; j < 4; j++) \
        Sw[sbase + j * 192 + (n)] = f2bf(acc[j] + bval); }

__global__ __launch_bounds__(128) void conv_up_mfma_kernel(const short* __restrict__ hbfp,
                                                           const short* __restrict__ Wp,
                                                           const float* __restrict__ bias,
                                                           short* __restrict__ U) {
    __shared__ short Sb[2][12288];       // 48 KB: per-wave out-staging (wave-private)
    int tid = threadIdx.x;
    int wave = tid >> 6, lane = tid & 63;
    int mt = blockIdx.x * 2 + wave;      // 512 strips: b(2) | y(64) | xt(4)
    int b = mt >> 8;
    int rem = mt & 255;
    int y = rem >> 2;
    int xt = rem & 3;
    int col = lane & 15;
    int g = lane >> 4;
    int x = xt * 16 + col;               // A-row pixel x

    const short* zb = hbfp + 2 * 66 * 66 * 48;   // 64 zero shorts

    // A fragments in registers, loaded once (same im2col addressing as before)
    short8v av[14];
    #pragma unroll
    for (int s = 0; s < 14; s++) {
        int gg = 4 * s + g;
        int tap = (gg * 171) >> 10;      // gg/6 for gg<60
        int cig = gg - tap * 6;
        int dy = (tap * 11) >> 5;        // tap/3 for tap<9(+)
        int dx = tap - dy * 3;
        const short* ap = hbfp + ((size_t)((b * 66 + y + dy) * 66 + (x + dx)) * 48 + cig * 8);
        ap = (gg < 54) ? ap : zb;
        av[s] = *(const short8v*)ap;
    }

    const short* Wb = Wp + col * 32 + g * 8;
    short* Sw = Sb[wave];
    int dyq = col >> 2, dxq = col & 3;
    int sbase = dyq * 3072 + (16 * g + dxq) * 48;   // + j*4*48 + n16

    short8v Ba[14], Bb[14];
    CU_LOADB(Ba, 0);
    for (int n = 0; n < 48; n += 2) {
        CU_LOADB(Bb, n + 1);
        CU_COMP(Ba, n);
        if (n + 2 < 48) CU_LOADB(Ba, n + 2);
        CU_COMP(Bb, n + 1);
    }

    // coalesced store: 4 rows x 3072 shorts contiguous each
    short* Ub = U + (((size_t)(b * 256 + 4 * y) * 256) + xt * 64) * 48;
    for (int i = lane; i < 1536; i += 64) {
        int row = i / 384;
        int w8 = i - row * 384;
        short8v v = *(const short8v*)(Sw + (size_t)i * 8);
        *(short8v*)(Ub + (size_t)row * 256 * 48 + w8 * 8) = v;
    }
}

// ---- zero bf16 pad regions; plant bf16 1.0 in Vr's padded row dd==12 (sum-row trick) ----
__global__ void zero16_kernel(u64* __restrict__ p, int n) {
    int i = blockIdx.x * 256 + threadIdx.x;
    if (i >= n) return;
    u64 fill = 0ull;
    // short offset of this 8-short chunk, relative to Vr start (Q:1M + K:1M shorts before it)
    int rel = 8 * i - 2097152;
    if (rel >= 0 && rel < 524288 && (((rel >> 5) & 15) == 12))
        fill = 0x3F803F803F803F80ull;     // bf16 1.0 x4
    p[2 * i] = fill;
    p[2 * i + 1] = fill;
}

// ---- fused: LN1 (NCHW) -> ln1 rows + qkv matmul -> bf16 Q/K/Vr (16-tok tiles) ----
__global__ __launch_bounds__(256) void fused_ln1_qkv_kernel(
    const float* __restrict__ hsrc, const float* __restrict__ g1, const float* __restrict__ b1,
    const float* __restrict__ w, const float* __restrict__ bias,
    float* __restrict__ ln1, short* __restrict__ Qbf, short* __restrict__ Kbf,
    short* __restrict__ Vr) {
    __shared__ float hs[48 * 17];
    __shared__ float lnr[16 * 49];
    __shared__ float wl[48 * 144];
    int blk = blockIdx.x;
    int b = blk >> 8;
    int pos0 = (blk & 255) * 16;
    int tid = threadIdx.x;

    for (int i = tid; i < 48 * 144; i += 256) wl[i] = w[i];
    for (int i = tid; i < 48 * 16; i += 256) {
        int ch = i >> 4, p = i & 15;
        hs[ch * 17 + p] = hsrc[((size_t)b * 48 + ch) * 4096 + pos0 + p];
    }
    __syncthreads();

    int tok = tid >> 4, oct = tid & 15;
    int pos = pos0 + tok;
    float v[3];
    float s = 0.f, s2 = 0.f;
    #pragma unroll
    for (int j = 0; j < 3; j++) {
        float x = hs[(oct * 3 + j) * 17 + tok];
        v[j] = x; s += x; s2 += x * x;
    }
    #pragma unroll
    for (int msk = 1; msk < 16; msk <<= 1) {
        s += __shfl_xor(s, msk, 64);
        s2 += __shfl_xor(s2, msk, 64);
    }
    float mu = s * (1.f / 48.f);
    float var = s2 * (1.f / 48.f) - mu * mu;
    float rs = rsqrtf(var + 1e-5f);
    float* go = ln1 + ((size_t)b * 4096 + pos) * 48 + oct * 3;
    #pragma unroll
    for (int j = 0; j < 3; j++) {
        int c = oct * 3 + j;
        float y = (v[j] - mu) * rs * g1[c] + b1[c];
        lnr[tok * 49 + c] = y;
        go[j] = y;
    }
    __syncthreads();

    int c0 = oct * 9;
    float acc[9];
    #pragma unroll
    for (int j = 0; j < 9; j++) acc[j] = bias[c0 + j];
    #pragma unroll 4
    for (int k = 0; k < 48; k++) {
        float a = lnr[tok * 49 + k];
        const float* wr = wl + k * 144 + c0;
        #pragma unroll
        for (int j = 0; j < 9; j++) acc[j] += a * wr[j];
    }

    // 1/sqrt(12) * log2(e): softmax exp becomes a single raw v_exp_f32 (2^x)
    const float scale = 0.41647023f;
    int sstep = pos >> 5, r = pos & 31;
    int g2 = (r < 16) ? (r >> 2) : ((r - 16) >> 2);
    int j2 = (r < 16) ? (r & 3) : 4 + ((r - 16) & 3);
    #pragma unroll
    for (int j = 0; j < 9; j++) {
        int c = c0 + j;
        int which = (c >= 96) ? 2 : (c >= 48 ? 1 : 0);
        int rem = c - which * 48;
        int hh = rem / 12;
        int dd = rem - hh * 12;
        int bh = b * 4 + hh;
        if (which == 0)
            Qbf[((size_t)bh * 4096 + pos) * 32 + dd] = f2bf(acc[j] * scale);
        else if (which == 1)
            Kbf[((size_t)bh * 4096 + pos) * 32 + dd] = f2bf(acc[j]);
        else
            Vr[((size_t)bh * 128 + sstep) * 512 + dd * 32 + g2 * 8 + j2] = f2bf(acc[j]);
    }
}

// ---- fused: split-combine + proj + resid + LN2 + fc1 + GELU + fc2 + resid + h-accum ----
__global__ __launch_bounds__(256) void fused_mlp_kernel(
    const float* __restrict__ opart, const float* __restrict__ ssump,
    const float* __restrict__ pwg, const float* __restrict__ pb,
    const float* __restrict__ ln1, const float* __restrict__ g2v, const float* __restrict__ b2v,
    const float* __restrict__ f1w, const float* __restrict__ f1b,
    const float* __restrict__ f2w, const float* __restrict__ f2b,
    float* __restrict__ hbuf) {
    __shared__ float sm[14640];
    float* wp  = sm;            // 2304  (48x48 proj)
    float* w1  = sm + 2304;     // 4608  (48x96 fc1)
    float* w2  = sm + 6912;     // 4608  (96x48 fc2)
    float* arf = sm + 11520;    // 784   (16x49) attn rows, reused as fc2-out
    float* lnr = sm + 12304;    // 784   (16x49) ln2 rows
    float* m1v = sm + 13088;    // 1552  (16x97) gelu(fc1)

    int blk = blockIdx.x;
    int b = blk >> 8;
    int pos0 = (blk & 255) * 16;
    int tid = threadIdx.x;

    for (int i = tid; i < 2304; i += 256) wp[i] = pwg[i];
    for (int i = tid; i < 4608; i += 256) w1[i] = f1w[i];
    for (int i = tid; i < 4608; i += 256) w2[i] = f2w[i];
    // combine split partials -> normalized attention rows (per-thread, no extra sync deps)
    for (int i = tid; i < 768; i += 256) {
        int t = i / 48, c = i - (i / 48) * 48;
        int hh = c / 12;
        size_t base = ((size_t)b * 4096 + pos0) * 48 + i;
        float stot = 0.f, s = 0.f;
        #pragma unroll
        for (int sp = 0; sp < NSPLIT; sp++) {
            stot += ssump[((size_t)sp * 8 + b * 4 + hh) * 4096 + pos0 + t];
            s += opart[base + (size_t)sp * OPART_STRIDE];
        }
        arf[t * 49 + c] = s / stot;
    }
    __syncthreads();

    int tok = tid >> 4, oct = tid & 15;
    size_t gtok = (size_t)b * 4096 + pos0 + tok;
    int c0 = oct * 3;
    float acc[3];
    #pragma unroll
    for (int j = 0; j < 3; j++) acc[j] = pb[c0 + j];
    #pragma unroll 4
    for (int k = 0; k < 48; k++) {
        float a = arf[tok * 49 + k];
        const float* wr = wp + k * 48 + c0;
        #pragma unroll
        for (int j = 0; j < 3; j++) acc[j] += a * wr[j];
    }
    const float* rp = ln1 + gtok * 48 + c0;
    float x[3]; float s = 0.f, s2 = 0.f;
    #pragma unroll
    for (int j = 0; j < 3; j++) {
        float t = acc[j] + rp[j];
        x[j] = t; s += t; s2 += t * t;
    }
    #pragma unroll
    for (int msk = 1; msk < 16; msk <<= 1) {
        s += __shfl_xor(s, msk, 64);
        s2 += __shfl_xor(s2, msk, 64);
    }
    float mu = s * (1.f / 48.f), var = s2 * (1.f / 48.f) - mu * mu;
    float rs = rsqrtf(var + 1e-5f);
    #pragma unroll
    for (int j = 0; j < 3; j++) {
        int c = c0 + j;
        lnr[tok * 49 + c] = (x[j] - mu) * rs * g2v[c] + b2v[c];
    }
    __syncthreads();

    // fc1 + GELU -> m1v (LDS only)
    int d0 = oct * 6;
    float a2[6];
    #pragma unroll
    for (int j = 0; j < 6; j++) a2[j] = f1b[d0 + j];
    #pragma unroll 4
    for (int k = 0; k < 48; k++) {
        float a = lnr[tok * 49 + k];
        const float* wr = w1 + k * 96 + d0;
        #pragma unroll
        for (int j = 0; j < 6; j++) a2[j] += a * wr[j];
    }
    #pragma unroll
    for (int j = 0; j < 6; j++) {
        float g = a2[j];
        m1v[tok * 97 + d0 + j] = 0.5f * g * (1.f + erff(g * 0.70710678118654752f));
    }
    __syncthreads();

    // fc2 + ln2-residual -> arf (reused)
    float f2acc[3];
    #pragma unroll
    for (int j = 0; j < 3; j++) f2acc[j] = f2b[c0 + j];
    #pragma unroll 4
    for (int k = 0; k < 96; k++) {
        float a = m1v[tok * 97 + k];
        const float* wr = w2 + k * 48 + c0;
        #pragma unroll
        for (int j = 0; j < 3; j++) f2acc[j] += a * wr[j];
    }
    __syncthreads();
    #pragma unroll
    for (int j = 0; j < 3; j++)
        arf[tok * 49 + c0 + j] = f2acc[j] + lnr[tok * 49 + c0 + j];
    __syncthreads();

    // cooperative coalesced transposed accumulate into h (NCHW)
    for (int i = tid; i < 768; i += 256) {
        int c = i >> 4, t = i & 15;
        hbuf[(((size_t)(b * 48 + c)) << 12) + pos0 + t] += arf[t * 49 + c];
    }
}

// ---- MFMA flash attention: 64 q/wave (4 fragments sharing K/V loads), split-K x4,
//      128-key chunk double-buffer (R1/R4-proven pipeline). No-max softmax: partials
//      (o, sum p) are plain sums -> additive combine in fused_mlp. Row sum via V
//      ones-row (dd==12). 4 frags quarter the L2 stream vs R3 (786 -> 196 MB). ----
#define LOADCH(P, c) { \
    _Pragma("unroll") \
    for (int s_ = 0; s_ < 4; s_++) { \
        const short* kp_ = Kb + ((size_t)((c) * 128 + s_ * 32 + col)) * 32 + g * 8; \
        P##k0[s_] = *(const short8v*)(kp_); \
        P##k1[s_] = *(const short8v*)(kp_ + 512); \
        P##v[s_]  = *(const short8v*)(Vrb + ((c) * 4 + s_) * 512 + vbase); \
    } }

#define STEP4(kc0, kc1, vv) { \
    _Pragma("unroll") \
    for (int f_ = 0; f_ < 4; f_++) { \
        f32x4 z_ = {0.f, 0.f, 0.f, 0.f}; \
        f32x4 s1 = __builtin_amdgcn_mfma_f32_16x16x32_bf16(kc0, qb[f_], z_, 0, 0, 0); \
        f32x4 s2 = __builtin_amdgcn_mfma_f32_16x16x32_bf16(kc1, qb[f_], z_, 0, 0, 0); \
        float p0 = exp2_raw(s1[0]), p1 = exp2_raw(s1[1]); \
        float p2 = exp2_raw(s1[2]), p3 = exp2_raw(s1[3]); \
        float p4 = exp2_raw(s2[0]), p5 = exp2_raw(s2[1]); \
        float p6 = exp2_raw(s2[2]), p7 = exp2_raw(s2[3]); \
        union { short8v sv; unsigned u[4]; } pu_; \
        asm("v_cvt_pk_bf16_f32 %0, %1, %2" : "=v"(pu_.u[0]) : "v"(p0), "v"(p1)); \
        asm("v_cvt_pk_bf16_f32 %0, %1, %2" : "=v"(pu_.u[1]) : "v"(p2), "v"(p3)); \
        asm("v_cvt_pk_bf16_f32 %0, %1, %2" : "=v"(pu_.u[2]) : "v"(p4), "v"(p5)); \
        asm("v_cvt_pk_bf16_f32 %0, %1, %2" : "=v"(pu_.u[3]) : "v"(p6), "v"(p7)); \
        o[f_] = __builtin_amdgcn_mfma_f32_16x16x32_bf16(vv, pu_.sv, o[f_], 0, 0, 0); \
    } }

#define COMPUTECH4(P) { \
    STEP4(P##k0[0], P##k1[0], P##v[0]); \
    STEP4(P##k0[1], P##k1[1], P##v[1]); \
    STEP4(P##k0[2], P##k1[2], P##v[2]); \
    STEP4(P##k0[3], P##k1[3], P##v[3]); }

__global__ __launch_bounds__(256) void attn_mfma_kernel(const short* __restrict__ Qbf,
                                                        const short* __restrict__ Kbf,
                                                        const short* __restrict__ Vr,
                                                        float* __restrict__ opart,
                                                        float* __restrict__ ssump) {
    int bid = blockIdx.x;                 // split(4) | qblk(16) | bh(8) = 512 blocks
    int bh = bid & 7;
    int qblk = (bid >> 3) & 15;
    int split = bid >> 7;
    int h = bh & 3, b = bh >> 2;
    int tid = threadIdx.x;
    int wave = tid >> 6;
    int lane = tid & 63;
    int q0 = qblk * 256 + wave * 64;      // 64 q per wave (4 x 16-q fragments)
    int col = lane & 15;
    int g = lane >> 4;

    const short* Kb  = Kbf + (size_t)bh * LL * 32 + (size_t)split * 1024 * 32;
    const short* Vrb = Vr + (size_t)bh * 65536 + (size_t)split * 32 * 512;
    int vbase = col * 32 + g * 8;

    short8v qb[4];
    f32x4 o[4];
    #pragma unroll
    for (int f = 0; f < 4; f++) {
        qb[f] = *(const short8v*)(Qbf + ((size_t)bh * LL + q0 + 16 * f + col) * 32 + g * 8);
        o[f] = (f32x4){0.f, 0.f, 0.f, 0.f};
    }

    short8v a_k0[4], a_k1[4], a_v[4];
    short8v b_k0[4], b_k1[4], b_v[4];

    LOADCH(a_, 0);
    for (int c = 0; c < 8; c += 2) {
        LOADCH(b_, c + 1);
        COMPUTECH4(a_);
        if (c + 2 < 8) LOADCH(a_, c + 2);
        COMPUTECH4(b_);
    }

    // row 12 of o (lane group g==3, j==0) holds this split's sum(p) via V's ones-row
    #pragma unroll
    for (int f = 0; f < 4; f++) {
        float ss = __shfl(o[f][0], 48 + col, 64);
        float* op = opart + (size_t)split * OPART_STRIDE
                  + ((size_t)b * 4096 + q0 + 16 * f + col) * 48 + h * HD;
        #pragma unroll
        for (int j = 0; j < 4; j++) {
            int d = 4 * g + j;
            if (d < HD)
                op[d] = o[f][j];
        }
        if (lane < 16)
            ssump[((size_t)split * 8 + bh) * 4096 + q0 + 16 * f + col] = ss;
    }
}

// ---- last conv as bf16 MFMA GEMM over channel-last U: M=131072 px, N=16 (3 real oc),
//      K=448 (tap*48+ci). Per-wave 16-px tile, 14 MFMAs, no LDS, no syncs. Boundary
//      taps resolved by zero-block pointer select (same idiom as conv_up's gg<54). ----
__global__ __launch_bounds__(256) void lastconv_mfma_kernel(const short* __restrict__ U,
                                                            const short* __restrict__ Wp2,
                                                            const short* __restrict__ zb,
                                                            const float* __restrict__ bias,
                                                            float* __restrict__ out) {
    int tid = threadIdx.x;
    int wave = tid >> 6, lane = tid & 63;
    int t = blockIdx.x * 4 + wave;        // 8192 tiles: b(2) | y(256) | xt(16)
    int xt = t & 15;
    int yy = (t >> 4) & 255;
    int b = t >> 12;
    int col = lane & 15, g = lane >> 4;
    int x = xt * 16 + col;                // A-row pixel x

    const short* Ub = U + (size_t)b * 65536 * 48;
    const short* Bp = Wp2 + col * 32 + g * 8;

    f32x4 acc = {0.f, 0.f, 0.f, 0.f};
    #pragma unroll
    for (int s = 0; s < 14; s++) {
        int gg = 4 * s + g;
        int tap = (gg * 171) >> 10;       // gg/6 for gg<60
        int cig = gg - tap * 6;
        int dy3 = (tap * 11) >> 5;        // tap/3 for tap<9(+)
        int dy = dy3 - 1;
        int dx = tap - dy3 * 3 - 1;
        int yq = yy + dy, xq = x + dx;
        bool ok = (gg < 54) && (yq >= 0) && (yq < 256) && (xq >= 0) && (xq < 256);
        const short* ap = Ub + (ptrdiff_t)(yq * 256 + xq) * 48 + cig * 8;
        ap = ok ? ap : zb;
        short8v av = *(const short8v*)ap;
        short8v bv = *(const short8v*)(Bp + s * 512);
        acc = __builtin_amdgcn_mfma_f32_16x16x32_bf16(av, bv, acc, 0, 0, 0);
    }

    if (col < 3) {
        float bval = bias[col];
        float* op = out + ((size_t)(b * 3 + col) * 256 + yy) * 256 + xt * 16 + 4 * g;
        #pragma unroll
        for (int j = 0; j < 4; j++)
            op[j] = acc[j] + bval;        // C row r=4g+j = pixel-x offset (m89 mapping)
    }
}

static inline int gs(int n) { return (n + 255) / 256; }

extern "C" void kernel_launch(void* const* d_in, const int* in_sizes, int n_in,
                              void* d_out, int out_size, void* d_ws, size_t ws_size,
                              hipStream_t stream) {
    const float* x    = (const float*)d_in[0];
    const float* cf_w = (const float*)d_in[1];
    const float* cf_b = (const float*)d_in[2];
    const float* n1g  = (const float*)d_in[3];
    const float* n1b  = (const float*)d_in[4];
    const float* qkvw = (const float*)d_in[5];
    const float* qkvb = (const float*)d_in[6];
    const float* pw   = (const float*)d_in[7];
    const float* pb   = (const float*)d_in[8];
    const float* n2g  = (const float*)d_in[9];
    const float* n2b  = (const float*)d_in[10];
    const float* f1w  = (const float*)d_in[11];
    const float* f1b  = (const float*)d_in[12];
    const float* f2w  = (const float*)d_in[13];
    const float* f2b  = (const float*)d_in[14];
    const float* upw  = (const float*)d_in[15];
    const float* upb  = (const float*)d_in[16];
    const float* lw   = (const float*)d_in[17];
    const float* lb   = (const float*)d_in[18];

    float* ws = (float*)d_ws;
    const int S_h = BB * D * LL;            // 393216
    float* A_h   = ws;
    float* pool  = ws + S_h;
    float* A_ln1 = pool;

    // U channel-last bf16: [b][256][256][48] shorts = 6291456 shorts = 3145728 floats at pool[0]
    // (written after the block loop; aliases A_ln1 + o_part, both dead by then)
    short* U_bf = (short*)pool;
    // attention split partials: o_part [4][B*L*48]
    float* o_part = pool + 1572864;                    // ends 3145728
    short* Qbf  = (short*)(pool + 3538944);
    short* Kbf  = Qbf + BB * NHEADS * LL * 32;         // +1048576 shorts
    short* Vr   = Kbf + BB * NHEADS * LL * 32;         // ends pool+4849664 floats
    // packs live in the dead gap after Vr (proven R3/R4 footprint, no growth)
    short* hbfp = (short*)(pool + 4849664);            // 418240 shorts -> ends 5058784
    short* Wp   = (short*)(pool + 5058784);            // 344064 shorts -> ends 5230816
    short* Wp2  = (short*)(pool + 5230816);            // 7168 shorts   -> ends 5234400
    // ssum partials
    float* ssum_part = pool + 5898240;                 // 131072 floats -> ends 6029312

    // conv_first (3 -> 48)
    conv3x3_kernel<<<gs(S_h), 256, 0, stream>>>(x, cf_w, cf_b, A_h, 3, D);

    // zero Q/K/Vr (pads must be 0; Vr ones-row planted; real entries overwritten every block)
    zero16_kernel<<<1536, 256, 0, stream>>>((u64*)Qbf, 393216);
    // pack conv_up + last-conv weights (input-only dependencies)
    pack_w_kernel<<<1344, 256, 0, stream>>>(upw, Wp);
    pack_lw_kernel<<<28, 256, 0, stream>>>(lw, Wp2);

    for (int i = 0; i < NBLK; i++) {
        fused_ln1_qkv_kernel<<<512, 256, 0, stream>>>(
            A_h, n1g + i * D, n1b + i * D,
            qkvw + (size_t)i * D * 3 * D, qkvb + i * 3 * D,
            A_ln1, Qbf, Kbf, Vr);
        attn_mfma_kernel<<<8 * 16 * NSPLIT, 256, 0, stream>>>(Qbf, Kbf, Vr, o_part, ssum_part);
        fused_mlp_kernel<<<512, 256, 0, stream>>>(
            o_part, ssum_part, pw + (size_t)i * D * D, pb + i * D,
            A_ln1, n2g + i * D, n2b + i * D,
            f1w + (size_t)i * D * 2 * D, f1b + i * 2 * D,
            f2w + (size_t)i * 2 * D * D, f2b + i * D,
            A_h);
    }

    // pack h -> bf16 halo'd channel-last, then reuse-restructured MFMA conv_up -> bf16 U
    pack_h_kernel<<<1634, 256, 0, stream>>>(A_h, hbfp);
    conv_up_mfma_kernel<<<256, 128, 0, stream>>>(hbfp, Wp, upb, U_bf);

    // last conv: MFMA im2col GEMM over channel-last bf16 U -> f32 out
    lastconv_mfma_kernel<<<2048, 256, 0, stream>>>(
        U_bf, Wp2, hbfp + 2 * 66 * 66 * 48, lb, (float*)d_out);
}